// Round 1
// baseline (2219.971 us; speedup 1.0000x reference)
//
#include <hip/hip_runtime.h>

#define B_  4096
#define C_  8
#define G_  978
#define D0_ 512
#define D1_ 256
#define D2_ 128
#define K_  512

// ---------------------------------------------------------------------------
// Generic tiled fp32 GEMM: C = [tanh](A @ B + bias), grouped over blockIdx.z.
// A: M x K, row stride aRow, group offset aGrp (in elements)
// B: K x N row-major contiguous (row stride == N), group offset bGrp
// bias: indexed by col, group offset biasGrp
// C: M x N, row stride cRow, group offset cGrp
// Block: 256 threads (16x16), each computes 4x4; tile 64x64, BK=16.
// M must be a multiple of 64 (true here: M=4096 always). N,K arbitrary.
// ---------------------------------------------------------------------------
__global__ __launch_bounds__(256) void gemm_bt(
    const float* __restrict__ A, int aRow, int aGrp,
    const float* __restrict__ Bm, int bGrp,
    const float* __restrict__ bias, int biasGrp,
    float* __restrict__ C, int cRow, int cGrp,
    int M, int N, int K, int doTanh)
{
    __shared__ float As[16][68];   // [k][row], +4 pad: conflict-free, 16B-aligned rows
    __shared__ float Bs[16][64];   // [k][col]

    const int g = blockIdx.z;
    const float* Ag = A  + (size_t)g * aGrp;
    const float* Bg = Bm + (size_t)g * bGrp;
    const float* bg = bias + (size_t)g * biasGrp;
    float* Cg = C + (size_t)g * cGrp;

    const int tid = threadIdx.x;
    const int tx = tid & 15, ty = tid >> 4;
    const int rowBase = blockIdx.y * 64;
    const int colBase = blockIdx.x * 64;

    float acc[4][4] = {};

    for (int k0 = 0; k0 < K; k0 += 16) {
        // A tile: 64 rows x 16 k
        #pragma unroll
        for (int i = 0; i < 4; ++i) {
            int e = tid + 256 * i;
            int r = e >> 4, kk = e & 15;
            int kg = k0 + kk;
            float v = 0.f;
            if (kg < K) v = Ag[(size_t)(rowBase + r) * aRow + kg];
            As[kk][r] = v;
        }
        // B tile: 16 k x 64 cols
        #pragma unroll
        for (int i = 0; i < 4; ++i) {
            int e = tid + 256 * i;
            int kk = e >> 6, c = e & 63;
            int kg = k0 + kk, cg = colBase + c;
            float v = 0.f;
            if (kg < K && cg < N) v = Bg[(size_t)kg * N + cg];
            Bs[kk][c] = v;
        }
        __syncthreads();
        #pragma unroll
        for (int kk = 0; kk < 16; ++kk) {
            float4 a4 = *(const float4*)&As[kk][ty * 4];
            float4 b4 = *(const float4*)&Bs[kk][tx * 4];
            float av[4] = {a4.x, a4.y, a4.z, a4.w};
            float bv[4] = {b4.x, b4.y, b4.z, b4.w};
            #pragma unroll
            for (int i = 0; i < 4; ++i)
                #pragma unroll
                for (int j = 0; j < 4; ++j)
                    acc[i][j] = fmaf(av[i], bv[j], acc[i][j]);
        }
        __syncthreads();
    }

    #pragma unroll
    for (int i = 0; i < 4; ++i) {
        int row = rowBase + ty * 4 + i;
        #pragma unroll
        for (int j = 0; j < 4; ++j) {
            int col = colBase + tx * 4 + j;
            if (col < N) {
                float v = acc[i][j] + bg[col];
                if (doTanh) v = tanhf(v);
                Cg[(size_t)row * cRow + col] = v;
            }
        }
    }
}

// ---------------------------------------------------------------------------
// VQ prep: per-code |cb_i|^2 in f64; zero the loss accumulator.
// ---------------------------------------------------------------------------
__global__ void vq_prep(const float* __restrict__ cb, double* __restrict__ csq,
                        double* __restrict__ acc)
{
    int i = threadIdx.x;              // 512 threads, one per code
    double s = 0.0;
    for (int d = 0; d < D2_; ++d) {
        double v = (double)cb[i * D2_ + d];
        s = fma(v, v, s);
    }
    csq[i] = s;
    if (i == 0) *acc = 0.0;
}

// ---------------------------------------------------------------------------
// VQ: one block per batch row. score_i = |cb_i|^2 - 2 z·cb_i in f64
// (drops the common |z|^2 term -> no large-magnitude rounding noise).
// argmin with first-index tie-break (np.argmin semantics).
// Emits q_st row (= codebook[idx]) and accumulates sum((q-z)^2).
// ---------------------------------------------------------------------------
__global__ __launch_bounds__(256) void vq_kernel(
    const float* __restrict__ z, const float* __restrict__ cb,
    const double* __restrict__ csq,
    float* __restrict__ qst_out, float* __restrict__ q_ws,
    double* __restrict__ acc)
{
    __shared__ float  zsh[D2_];
    __shared__ double sval[256];
    __shared__ int    sidx[256];
    __shared__ float  lsum[256];

    const int b = blockIdx.x;
    const int t = threadIdx.x;

    if (t < D2_) zsh[t] = z[(size_t)b * D2_ + t];
    __syncthreads();

    double best = 1e300; int bidx = 0x7fffffff;
    for (int i = t; i < K_; i += 256) {
        double dot = 0.0;
        #pragma unroll 4
        for (int d = 0; d < D2_; ++d)
            dot = fma((double)cb[i * D2_ + d], (double)zsh[d], dot);
        double s = csq[i] - 2.0 * dot;
        if (s < best || (s == best && i < bidx)) { best = s; bidx = i; }
    }
    sval[t] = best; sidx[t] = bidx;
    __syncthreads();
    for (int off = 128; off > 0; off >>= 1) {
        if (t < off) {
            double ov = sval[t + off]; int oi = sidx[t + off];
            if (ov < sval[t] || (ov == sval[t] && oi < sidx[t])) {
                sval[t] = ov; sidx[t] = oi;
            }
        }
        __syncthreads();
    }
    const int idx = sidx[0];

    float part = 0.f;
    if (t < D2_) {
        float qv = cb[idx * D2_ + t];
        qst_out[(size_t)b * D2_ + t] = qv;
        q_ws[(size_t)b * D2_ + t] = qv;
        float d = qv - zsh[t];
        part = d * d;
    }
    lsum[t] = part;
    __syncthreads();
    for (int off = 128; off > 0; off >>= 1) {
        if (t < off) lsum[t] += lsum[t + off];
        __syncthreads();
    }
    if (t == 0) atomicAdd(acc, (double)lsum[0]);
}

__global__ void finalize_loss(const double* __restrict__ acc, float* __restrict__ out0)
{
    // loss = q_latent + COM * e_latent = 1.25 * mean((q - z)^2)
    out0[0] = (float)(1.25 * (*acc) / (double)((size_t)B_ * D2_));
}

// ---------------------------------------------------------------------------
extern "C" void kernel_launch(void* const* d_in, const int* in_sizes, int n_in,
                              void* d_out, int out_size, void* d_ws, size_t ws_size,
                              hipStream_t stream)
{
    const float* inputs = (const float*)d_in[0];
    const float* enc_w  = (const float*)d_in[1];
    const float* enc_b  = (const float*)d_in[2];
    const float* w1     = (const float*)d_in[3];
    const float* b1     = (const float*)d_in[4];
    const float* w2     = (const float*)d_in[5];
    const float* b2     = (const float*)d_in[6];
    const float* cb     = (const float*)d_in[7];
    const float* dw1    = (const float*)d_in[8];
    const float* db1    = (const float*)d_in[9];
    const float* dw2    = (const float*)d_in[10];
    const float* db2    = (const float*)d_in[11];
    const float* dec_w  = (const float*)d_in[12];
    const float* dec_b  = (const float*)d_in[13];

    float* out = (float*)d_out;
    float* x_recon = out + 1;
    float* qst     = out + 1 + (size_t)B_ * C_ * G_;

    // workspace layout (fp32 unless noted); h reused as r, z1 reused as r1
    float*  h   = (float*)d_ws;                       // B x 4096
    float*  z1  = h  + (size_t)B_ * (C_ * D0_);       // B x 256
    float*  z   = z1 + (size_t)B_ * D1_;              // B x 128
    float*  q   = z  + (size_t)B_ * D2_;              // B x 128
    double* csq = (double*)(q + (size_t)B_ * D2_);    // 512 f64
    double* acc = csq + K_;                           // 1 f64

    dim3 blk(256);

    // K1: h = tanh(inputs @ enc_w + enc_b)   (grouped, C=8)
    gemm_bt<<<dim3(D0_ / 64, B_ / 64, C_), blk, 0, stream>>>(
        inputs, C_ * G_, G_, enc_w, G_ * D0_, enc_b, D0_,
        h, C_ * D0_, D0_, B_, D0_, G_, 1);

    // K2: z1 = tanh(h @ w1 + b1)
    gemm_bt<<<dim3(D1_ / 64, B_ / 64, 1), blk, 0, stream>>>(
        h, C_ * D0_, 0, w1, 0, b1, 0,
        z1, D1_, 0, B_, D1_, C_ * D0_, 1);

    // K3: z = tanh(z1 @ w2 + b2)
    gemm_bt<<<dim3(D2_ / 64, B_ / 64, 1), blk, 0, stream>>>(
        z1, D1_, 0, w2, 0, b2, 0,
        z, D2_, 0, B_, D2_, D1_, 1);

    // VQ
    vq_prep<<<dim3(1), dim3(K_), 0, stream>>>(cb, csq, acc);
    vq_kernel<<<dim3(B_), blk, 0, stream>>>(z, cb, csq, qst, q, acc);

    // K5: r1 = tanh(q @ dw1 + db1)   (z1 buffer reused as r1)
    gemm_bt<<<dim3(D1_ / 64, B_ / 64, 1), blk, 0, stream>>>(
        q, D2_, 0, dw1, 0, db1, 0,
        z1, D1_, 0, B_, D1_, D2_, 1);

    // K6: r = tanh(r1 @ dw2 + db2)   (h buffer reused as r)
    gemm_bt<<<dim3((C_ * D0_) / 64, B_ / 64, 1), blk, 0, stream>>>(
        z1, D1_, 0, dw2, 0, db2, 0,
        h, C_ * D0_, 0, B_, C_ * D0_, D1_, 1);

    // K7: x_recon = r @ dec_w + dec_b  (grouped, no tanh)
    gemm_bt<<<dim3((G_ + 63) / 64, B_ / 64, C_), blk, 0, stream>>>(
        h, C_ * D0_, D0_, dec_w, D0_ * G_, dec_b, G_,
        x_recon, C_ * G_, G_, B_, G_, D0_, 0);

    finalize_loss<<<dim3(1), dim3(1), 0, stream>>>(acc, out);
}

// Round 2
// 884.927 us; speedup vs baseline: 2.5086x; 2.5086x over previous
//
#include <hip/hip_runtime.h>

#define B_   4096
#define C_   8
#define G_   978
#define D0_  512
#define D1_  256
#define D2_  128
#define K_   512
#define KP_  1024          // padded G (K of enc GEMM)
#define CD_  4096          // C_*D0_

typedef short short8 __attribute__((ext_vector_type(8)));
typedef float f32x4  __attribute__((ext_vector_type(4)));

// ---------------- bf16 helpers (RNE) ----------------
__device__ __forceinline__ unsigned short f2bf(float v) {
    union { float f; unsigned u; } x; x.f = v;
    unsigned r = (x.u + 0x7fffu + ((x.u >> 16) & 1u)) >> 16;
    return (unsigned short)r;
}
__device__ __forceinline__ float bf2f(unsigned short b) {
    union { unsigned u; float f; } x; x.u = ((unsigned)b) << 16;
    return x.f;
}

__device__ __forceinline__ void gload16(const unsigned short* g, unsigned short* l) {
    typedef const __attribute__((address_space(1))) unsigned int* gp_t;
    typedef __attribute__((address_space(3))) unsigned int* lp_t;
    __builtin_amdgcn_global_load_lds((gp_t)(const void*)g, (lp_t)(void*)l, 16, 0, 0);
}

// ---------------------------------------------------------------------------
// Split-bf16 MFMA GEMM: C = [tanh]( (Ahi+Alo) @ (Bhi+Blo)^T_rows + bias )
// A: [M][lda] rows of K (per group offset aGrpK along k)
// B: stored transposed Bt[N][ldb] rows of K (per group offset bGrp elements)
// 3 passes: hi*hi, hi*lo, lo*hi accumulate into the same fp32 acc.
// Tile 128x128, BK=64, 256 threads = 4 waves (2x2), 16x16x32 bf16 MFMA.
// If kSplit: blockIdx.z = K-slice (kStart = z*kLen), group = 0.
// Output: fp32 (Cf) or split-bf16 (Chi/Clo), offset z*cGrp, stride ldc.
// ---------------------------------------------------------------------------
template<int DO_TANH, int OUT_SPLIT>
__global__ __launch_bounds__(256, 2) void mfma_gemm(
    const unsigned short* __restrict__ Ahi, const unsigned short* __restrict__ Alo,
    int lda, int aGrpK,
    const unsigned short* __restrict__ Bhi, const unsigned short* __restrict__ Blo,
    int ldb, int bGrp,
    const float* __restrict__ bias, int biasGrp,
    float* __restrict__ Cf, unsigned short* __restrict__ Chi, unsigned short* __restrict__ Clo,
    int ldc, long long cGrp,
    int N, int kLen, int kSplit)
{
    __shared__ __align__(16) unsigned short As[128 * 64];
    __shared__ __align__(16) unsigned short Bs[128 * 64];

    const int z = blockIdx.z;
    const int g = kSplit ? 0 : z;
    const int kStart = kSplit ? z * kLen : 0;
    const size_t aOff = (size_t)g * aGrpK;
    const size_t bOff = (size_t)g * bGrp;
    const size_t cOff = (size_t)z * cGrp;
    const int bias0 = g * biasGrp;

    const int t = threadIdx.x;
    const int rh = t >> 3;          // 0..31: row within 32-row staging stripe
    const int ch = t & 7;           // 16B chunk within 64-elem row
    const int rowBase = blockIdx.y * 128;
    const int colBase = blockIdx.x * 128;

    const int wv = t >> 6, wm = wv >> 1, wn = wv & 1;
    const int l = t & 63, lr = l & 15, lk = l >> 4;

    f32x4 acc[4][4] = {};

    for (int pass = 0; pass < 3; ++pass) {
        const unsigned short* pA = (pass == 2) ? Alo : Ahi;
        const unsigned short* pB = (pass == 1) ? Blo : Bhi;
        for (int k0 = 0; k0 < kLen; k0 += 64) {
            const unsigned short* aS = pA + aOff + (size_t)(rowBase + rh) * lda + kStart + k0 + ch * 8;
            unsigned short* aD = &As[rh * 64 + ch * 8];
            #pragma unroll
            for (int it = 0; it < 4; ++it)
                gload16(aS + (size_t)(32 * it) * lda, aD + it * 2048);
            #pragma unroll
            for (int it = 0; it < 4; ++it) {
                int bn = colBase + rh + 32 * it; bn = bn < N ? bn : N - 1;
                gload16(pB + bOff + (size_t)bn * ldb + kStart + k0 + ch * 8,
                        &Bs[(rh + 32 * it) * 64 + ch * 8]);
            }
            __syncthreads();
            #pragma unroll
            for (int s = 0; s < 2; ++s) {
                short8 af[4], bf[4];
                #pragma unroll
                for (int i = 0; i < 4; ++i)
                    af[i] = *(const short8*)&As[(wm * 64 + i * 16 + lr) * 64 + s * 32 + lk * 8];
                #pragma unroll
                for (int j = 0; j < 4; ++j)
                    bf[j] = *(const short8*)&Bs[(wn * 64 + j * 16 + lr) * 64 + s * 32 + lk * 8];
                #pragma unroll
                for (int i = 0; i < 4; ++i)
                    #pragma unroll
                    for (int j = 0; j < 4; ++j)
                        acc[i][j] = __builtin_amdgcn_mfma_f32_16x16x32_bf16(af[i], bf[j], acc[i][j], 0, 0, 0);
            }
            __syncthreads();
        }
    }

    #pragma unroll
    for (int i = 0; i < 4; ++i) {
        #pragma unroll
        for (int j = 0; j < 4; ++j) {
            #pragma unroll
            for (int r = 0; r < 4; ++r) {
                int row = rowBase + wm * 64 + i * 16 + lk * 4 + r;
                int col = colBase + wn * 64 + j * 16 + lr;
                if (col < N) {
                    float v = acc[i][j][r];
                    if (bias) v += bias[bias0 + col];
                    if (DO_TANH) v = tanhf(v);
                    size_t off = cOff + (size_t)row * ldc + col;
                    if (OUT_SPLIT) {
                        unsigned short hh = f2bf(v);
                        Chi[off] = hh;
                        Clo[off] = f2bf(v - bf2f(hh));
                    } else {
                        Cf[off] = v;
                    }
                }
            }
        }
    }
}

// ---------------------------------------------------------------------------
// inputs split: [32768 rows][978] fp32 -> [32768][1024] bf16 hi/lo, zero-pad.
// 2 elems/thread, packed 4B stores. grid.x = 32768*2.
// ---------------------------------------------------------------------------
__global__ void split_rows_in(const float* __restrict__ src,
                              unsigned short* __restrict__ hi,
                              unsigned short* __restrict__ lo)
{
    int o = blockIdx.x >> 1;
    int c = ((blockIdx.x & 1) * 256 + threadIdx.x) * 2;
    const float* s = src + (size_t)o * G_;
    size_t d = (size_t)o * KP_ + c;
    float v0 = (c     < G_) ? s[c]     : 0.f;
    float v1 = (c + 1 < G_) ? s[c + 1] : 0.f;
    unsigned short h0 = f2bf(v0), h1 = f2bf(v1);
    unsigned short l0 = f2bf(v0 - bf2f(h0)), l1 = f2bf(v1 - bf2f(h1));
    *(unsigned int*)&hi[d] = (unsigned)h0 | ((unsigned)h1 << 16);
    *(unsigned int*)&lo[d] = (unsigned)l0 | ((unsigned)l1 << 16);
}

// ---------------------------------------------------------------------------
// weight transpose + split (+K pad): src fp32 [g][Ksrc][N] -> bf16 [g][N][Kdst]
// grid: (ceil(N/32), ceil(Kdst/32), groups), 256 threads (32x8), LDS 32x33.
// ---------------------------------------------------------------------------
__global__ void transpose_split(const float* __restrict__ src, long long sGrp,
                                unsigned short* __restrict__ hi, unsigned short* __restrict__ lo,
                                long long dGrp, int Ksrc, int Kdst, int N)
{
    __shared__ float tile[32][33];
    int g = blockIdx.z;
    int k0 = blockIdx.y * 32, n0 = blockIdx.x * 32;
    int tx = threadIdx.x & 31, ty = threadIdx.x >> 5;
    #pragma unroll
    for (int i = 0; i < 4; ++i) {
        int k = k0 + ty + 8 * i, n = n0 + tx;
        float v = 0.f;
        if (k < Ksrc && n < N) v = src[(size_t)g * sGrp + (size_t)k * N + n];
        tile[ty + 8 * i][tx] = v;
    }
    __syncthreads();
    #pragma unroll
    for (int i = 0; i < 4; ++i) {
        int n = n0 + ty + 8 * i, k = k0 + tx;
        if (n < N && k < Kdst) {
            float v = tile[tx][ty + 8 * i];
            unsigned short h = f2bf(v);
            size_t off = (size_t)g * dGrp + (size_t)n * Kdst + k;
            hi[off] = h;
            lo[off] = f2bf(v - bf2f(h));
        }
    }
}

// combine split-K partials of K2: z1 = tanh(sum_z P[z] + b1)
__global__ void combine4_tanh(const float* __restrict__ P, const float* __restrict__ b1,
                              float* __restrict__ z1)
{
    const int MN = B_ * D1_;
    int i = blockIdx.x * 256 + threadIdx.x;
    float v = P[i] + P[i + MN] + P[i + 2 * MN] + P[i + 3 * MN] + b1[i & (D1_ - 1)];
    z1[i] = tanhf(v);
}

// ---------------------------------------------------------------------------
// fp32 vector GEMM (round-1), for the two tiny GEMMs K3/K5; optional split-out.
// ---------------------------------------------------------------------------
__global__ __launch_bounds__(256) void gemm_bt(
    const float* __restrict__ A, int aRow, int aGrp,
    const float* __restrict__ Bm, int bGrp,
    const float* __restrict__ bias, int biasGrp,
    float* __restrict__ C, int cRow, int cGrp,
    int M, int N, int K, int doTanh,
    unsigned short* __restrict__ Shi, unsigned short* __restrict__ Slo)
{
    __shared__ float As[16][68];
    __shared__ float Bs[16][64];

    const int g = blockIdx.z;
    const float* Ag = A  + (size_t)g * aGrp;
    const float* Bg = Bm + (size_t)g * bGrp;
    const float* bg = bias + (size_t)g * biasGrp;

    const int tid = threadIdx.x;
    const int tx = tid & 15, ty = tid >> 4;
    const int rowBase = blockIdx.y * 64;
    const int colBase = blockIdx.x * 64;

    float acc[4][4] = {};

    for (int k0 = 0; k0 < K; k0 += 16) {
        #pragma unroll
        for (int i = 0; i < 4; ++i) {
            int e = tid + 256 * i;
            int r = e >> 4, kk = e & 15;
            int kg = k0 + kk;
            float v = 0.f;
            if (kg < K) v = Ag[(size_t)(rowBase + r) * aRow + kg];
            As[kk][r] = v;
        }
        #pragma unroll
        for (int i = 0; i < 4; ++i) {
            int e = tid + 256 * i;
            int kk = e >> 6, c = e & 63;
            int kg = k0 + kk, cg = colBase + c;
            float v = 0.f;
            if (kg < K && cg < N) v = Bg[(size_t)kg * N + cg];
            Bs[kk][c] = v;
        }
        __syncthreads();
        #pragma unroll
        for (int kk = 0; kk < 16; ++kk) {
            float4 a4 = *(const float4*)&As[kk][ty * 4];
            float4 b4 = *(const float4*)&Bs[kk][tx * 4];
            float av[4] = {a4.x, a4.y, a4.z, a4.w};
            float bv[4] = {b4.x, b4.y, b4.z, b4.w};
            #pragma unroll
            for (int i = 0; i < 4; ++i)
                #pragma unroll
                for (int j = 0; j < 4; ++j)
                    acc[i][j] = fmaf(av[i], bv[j], acc[i][j]);
        }
        __syncthreads();
    }

    #pragma unroll
    for (int i = 0; i < 4; ++i) {
        int row = rowBase + ty * 4 + i;
        #pragma unroll
        for (int j = 0; j < 4; ++j) {
            int col = colBase + tx * 4 + j;
            if (col < N) {
                float v = acc[i][j] + bg[col];
                if (doTanh) v = tanhf(v);
                size_t off = (size_t)g * cGrp + (size_t)row * cRow + col;
                if (Shi) {
                    unsigned short h = f2bf(v);
                    Shi[off] = h;
                    Slo[off] = f2bf(v - bf2f(h));
                } else {
                    C[off] = v;
                }
            }
        }
    }
}

// ---------------- VQ (unchanged from round 1, f64 scores) ----------------
__global__ void vq_prep(const float* __restrict__ cb, double* __restrict__ csq,
                        double* __restrict__ acc)
{
    int i = threadIdx.x;
    double s = 0.0;
    for (int d = 0; d < D2_; ++d) {
        double v = (double)cb[i * D2_ + d];
        s = fma(v, v, s);
    }
    csq[i] = s;
    if (i == 0) *acc = 0.0;
}

__global__ __launch_bounds__(256) void vq_kernel(
    const float* __restrict__ z, const float* __restrict__ cb,
    const double* __restrict__ csq,
    float* __restrict__ qst_out, float* __restrict__ q_ws,
    double* __restrict__ acc)
{
    __shared__ float  zsh[D2_];
    __shared__ double sval[256];
    __shared__ int    sidx[256];
    __shared__ float  lsum[256];

    const int b = blockIdx.x;
    const int t = threadIdx.x;

    if (t < D2_) zsh[t] = z[(size_t)b * D2_ + t];
    __syncthreads();

    double best = 1e300; int bidx = 0x7fffffff;
    for (int i = t; i < K_; i += 256) {
        double dot = 0.0;
        #pragma unroll 4
        for (int d = 0; d < D2_; ++d)
            dot = fma((double)cb[i * D2_ + d], (double)zsh[d], dot);
        double s = csq[i] - 2.0 * dot;
        if (s < best || (s == best && i < bidx)) { best = s; bidx = i; }
    }
    sval[t] = best; sidx[t] = bidx;
    __syncthreads();
    for (int off = 128; off > 0; off >>= 1) {
        if (t < off) {
            double ov = sval[t + off]; int oi = sidx[t + off];
            if (ov < sval[t] || (ov == sval[t] && oi < sidx[t])) {
                sval[t] = ov; sidx[t] = oi;
            }
        }
        __syncthreads();
    }
    const int idx = sidx[0];

    float part = 0.f;
    if (t < D2_) {
        float qv = cb[idx * D2_ + t];
        qst_out[(size_t)b * D2_ + t] = qv;
        q_ws[(size_t)b * D2_ + t] = qv;
        float d = qv - zsh[t];
        part = d * d;
    }
    lsum[t] = part;
    __syncthreads();
    for (int off = 128; off > 0; off >>= 1) {
        if (t < off) lsum[t] += lsum[t + off];
        __syncthreads();
    }
    if (t == 0) atomicAdd(acc, (double)lsum[0]);
}

__global__ void finalize_loss(const double* __restrict__ acc, float* __restrict__ out0)
{
    out0[0] = (float)(1.25 * (*acc) / (double)((size_t)B_ * D2_));
}

// ---------------------------------------------------------------------------
extern "C" void kernel_launch(void* const* d_in, const int* in_sizes, int n_in,
                              void* d_out, int out_size, void* d_ws, size_t ws_size,
                              hipStream_t stream)
{
    const float* inputs = (const float*)d_in[0];
    const float* enc_w  = (const float*)d_in[1];
    const float* enc_b  = (const float*)d_in[2];
    const float* w1     = (const float*)d_in[3];
    const float* b1     = (const float*)d_in[4];
    const float* w2     = (const float*)d_in[5];
    const float* b2     = (const float*)d_in[6];
    const float* cb     = (const float*)d_in[7];
    const float* dw1    = (const float*)d_in[8];
    const float* db1    = (const float*)d_in[9];
    const float* dw2    = (const float*)d_in[10];
    const float* db2    = (const float*)d_in[11];
    const float* dec_w  = (const float*)d_in[12];
    const float* dec_b  = (const float*)d_in[13];

    float* out = (float*)d_out;
    float* x_recon = out + 1;
    float* qst     = out + 1 + (size_t)B_ * C_ * G_;

    const size_t MB = 1u << 20;
    const size_t NEED = 208 * MB;
    dim3 blk(256);

    if (ws_size >= NEED) {
        char* W = (char*)d_ws;
        unsigned short* ipad_hi = (unsigned short*)(W + 0);        // 64MB (dead after K1)
        unsigned short* ipad_lo = (unsigned short*)(W + 64 * MB);  // 64MB
        unsigned short* h_hi    = (unsigned short*)(W + 128 * MB); // 32MB
        unsigned short* h_lo    = (unsigned short*)(W + 160 * MB); // 32MB
        unsigned short* ewt_hi  = (unsigned short*)(W + 192 * MB); // 8MB
        unsigned short* ewt_lo  = (unsigned short*)(W + 200 * MB); // 8MB
        // region A reuse after K1:
        unsigned short* w1t_hi  = (unsigned short*)(W + 0);
        unsigned short* w1t_lo  = (unsigned short*)(W + 2 * MB);
        unsigned short* dw2t_hi = (unsigned short*)(W + 4 * MB);
        unsigned short* dw2t_lo = (unsigned short*)(W + 6 * MB);
        unsigned short* dwt_hi  = (unsigned short*)(W + 8 * MB);   // dec_wt 7.65MB
        unsigned short* dwt_lo  = (unsigned short*)(W + 16 * MB);
        float* partials = (float*)(W + 24 * MB);                   // 16MB
        float* z1 = (float*)(W + 40 * MB);                         // 4MB
        float* z  = (float*)(W + 44 * MB);                         // 2MB
        float* q  = (float*)(W + 46 * MB);                         // 2MB
        unsigned short* r1_hi = (unsigned short*)(W + 48 * MB);
        unsigned short* r1_lo = (unsigned short*)(W + 50 * MB);
        unsigned short* r_hi  = (unsigned short*)(W + 52 * MB);    // 32MB
        unsigned short* r_lo  = (unsigned short*)(W + 84 * MB);    // 32MB -> ends 116MB
        double* csq = (double*)(W + 116 * MB);
        double* acc = (double*)(W + 116 * MB + 8192);

        // inputs -> padded split bf16
        split_rows_in<<<dim3(B_ * C_ * 2), blk, 0, stream>>>(inputs, ipad_hi, ipad_lo);
        // enc_w [8][978][512] -> [8][512][1024]
        transpose_split<<<dim3(16, 32, 8), blk, 0, stream>>>(
            enc_w, (long long)G_ * D0_, ewt_hi, ewt_lo, (long long)D0_ * KP_, G_, KP_, D0_);

        // K1: h = tanh(inputs @ enc_w + enc_b), split-bf16 out
        mfma_gemm<1, 1><<<dim3(4, 32, 8), blk, 0, stream>>>(
            ipad_hi, ipad_lo, C_ * KP_, KP_,
            ewt_hi, ewt_lo, KP_, D0_ * KP_,
            enc_b, D0_,
            nullptr, h_hi, h_lo, CD_, 512LL,
            D0_, KP_, 0);

        // remaining weight transposes (into region A, ipad now dead)
        transpose_split<<<dim3(8, 128, 1), blk, 0, stream>>>(
            w1, 0, w1t_hi, w1t_lo, 0, CD_, CD_, D1_);
        transpose_split<<<dim3(128, 8, 1), blk, 0, stream>>>(
            dw2, 0, dw2t_hi, dw2t_lo, 0, D1_, D1_, CD_);
        transpose_split<<<dim3(31, 16, 8), blk, 0, stream>>>(
            dec_w, (long long)D0_ * G_, dwt_hi, dwt_lo, (long long)G_ * D0_, D0_, D0_, G_);

        // K2: partials[z] = h @ w1 (split-K = 4)
        mfma_gemm<0, 0><<<dim3(2, 32, 4), blk, 0, stream>>>(
            h_hi, h_lo, CD_, 0,
            w1t_hi, w1t_lo, CD_, 0,
            nullptr, 0,
            partials, nullptr, nullptr, D1_, (long long)B_ * D1_,
            D1_, CD_ / 4, 1);
        combine4_tanh<<<dim3(B_ * D1_ / 256), blk, 0, stream>>>(partials, b1, z1);

        // K3: z = tanh(z1 @ w2 + b2)  (fp32)
        gemm_bt<<<dim3(2, 64, 1), blk, 0, stream>>>(
            z1, D1_, 0, w2, 0, b2, 0, z, D2_, 0, B_, D2_, D1_, 1, nullptr, nullptr);

        // VQ
        vq_prep<<<dim3(1), dim3(K_), 0, stream>>>(cb, csq, acc);
        vq_kernel<<<dim3(B_), blk, 0, stream>>>(z, cb, csq, qst, q, acc);

        // K5: r1 = tanh(q @ dw1 + db1)  (fp32, split-bf16 out)
        gemm_bt<<<dim3(4, 64, 1), blk, 0, stream>>>(
            q, D2_, 0, dw1, 0, db1, 0, nullptr, D1_, 0, B_, D1_, D2_, 1, r1_hi, r1_lo);

        // K6: r = tanh(r1 @ dw2 + db2), split-bf16 out
        mfma_gemm<1, 1><<<dim3(32, 32, 1), blk, 0, stream>>>(
            r1_hi, r1_lo, D1_, 0,
            dw2t_hi, dw2t_lo, D1_, 0,
            db2, 0,
            nullptr, r_hi, r_lo, CD_, 0LL,
            CD_, D1_, 0);

        // K7: x_recon = r @ dec_w + dec_b (grouped, fp32 out, N=978 edge)
        mfma_gemm<0, 0><<<dim3(8, 32, 8), blk, 0, stream>>>(
            r_hi, r_lo, CD_, D0_,
            dwt_hi, dwt_lo, D0_, G_ * D0_,
            dec_b, G_,
            x_recon, nullptr, nullptr, C_ * G_, (long long)G_,
            G_, D0_, 0);

        finalize_loss<<<dim3(1), dim3(1), 0, stream>>>(acc, out);
    } else {
        // -------- fallback: round-1 fp32 path --------
        float*  h   = (float*)d_ws;
        float*  z1  = h  + (size_t)B_ * CD_;
        float*  z   = z1 + (size_t)B_ * D1_;
        float*  q   = z  + (size_t)B_ * D2_;
        double* csq = (double*)(q + (size_t)B_ * D2_);
        double* acc = csq + K_;

        gemm_bt<<<dim3(D0_ / 64, B_ / 64, C_), blk, 0, stream>>>(
            inputs, C_ * G_, G_, enc_w, G_ * D0_, enc_b, D0_,
            h, CD_, D0_, B_, D0_, G_, 1, nullptr, nullptr);
        gemm_bt<<<dim3(D1_ / 64, B_ / 64, 1), blk, 0, stream>>>(
            h, CD_, 0, w1, 0, b1, 0, z1, D1_, 0, B_, D1_, CD_, 1, nullptr, nullptr);
        gemm_bt<<<dim3(D2_ / 64, B_ / 64, 1), blk, 0, stream>>>(
            z1, D1_, 0, w2, 0, b2, 0, z, D2_, 0, B_, D2_, D1_, 1, nullptr, nullptr);
        vq_prep<<<dim3(1), dim3(K_), 0, stream>>>(cb, csq, acc);
        vq_kernel<<<dim3(B_), blk, 0, stream>>>(z, cb, csq, qst, q, acc);
        gemm_bt<<<dim3(D1_ / 64, B_ / 64, 1), blk, 0, stream>>>(
            q, D2_, 0, dw1, 0, db1, 0, z1, D1_, 0, B_, D1_, D2_, 1, nullptr, nullptr);
        gemm_bt<<<dim3(CD_ / 64, B_ / 64, 1), blk, 0, stream>>>(
            z1, D1_, 0, dw2, 0, db2, 0, h, CD_, 0, B_, CD_, D1_, 1, nullptr, nullptr);
        gemm_bt<<<dim3((G_ + 63) / 64, B_ / 64, C_), blk, 0, stream>>>(
            h, CD_, D0_, dec_w, D0_ * G_, dec_b, G_,
            x_recon, C_ * G_, G_, B_, G_, D0_, 0, nullptr, nullptr);
        finalize_loss<<<dim3(1), dim3(1), 0, stream>>>(acc, out);
    }
}

// Round 3
// 561.491 us; speedup vs baseline: 3.9537x; 1.5760x over previous
//
#include <hip/hip_runtime.h>

#define B_   4096
#define C_   8
#define G_   978
#define D0_  512
#define D1_  256
#define D2_  128
#define K_   512
#define KP_  1024          // padded G (K of enc GEMM)
#define CD_  4096          // C_*D0_

typedef short short8 __attribute__((ext_vector_type(8)));
typedef float f32x4  __attribute__((ext_vector_type(4)));

// ---------------- bf16 helpers (RNE) ----------------
__device__ __forceinline__ unsigned short f2bf(float v) {
    union { float f; unsigned u; } x; x.f = v;
    unsigned r = (x.u + 0x7fffu + ((x.u >> 16) & 1u)) >> 16;
    return (unsigned short)r;
}
__device__ __forceinline__ float bf2f(unsigned short b) {
    union { unsigned u; float f; } x; x.u = ((unsigned)b) << 16;
    return x.f;
}

__device__ __forceinline__ void gload16(const unsigned short* g, unsigned short* l) {
    typedef const __attribute__((address_space(1))) unsigned int* gp_t;
    typedef __attribute__((address_space(3))) unsigned int* lp_t;
    __builtin_amdgcn_global_load_lds((gp_t)(const void*)g, (lp_t)(void*)l, 16, 0, 0);
}

// ---------------------------------------------------------------------------
// Split-bf16 MFMA GEMM, FUSED: C = [tanh]( (Ahi+Alo) @ (Bhi+Blo)^T + bias )
// One K-loop stages Ahi/Alo/Bhi/Blo tiles; 3 products (hh, hl, lh) per tile.
// Tile 128x128, BK=64, 256 threads = 4 waves (2x2), 16x16x32 bf16 MFMA.
// LDS XOR-swizzle: global_load_lds dest is linear; SOURCE chunk is
// pre-swizzled (ch ^ (row&7)); reads apply the same XOR (rule #21).
// XCD-aware bijective blockIdx remap (grids here all have nwg % 8 == 0).
// ---------------------------------------------------------------------------
template<int DO_TANH, int OUT_SPLIT>
__global__ __launch_bounds__(256, 2) void mfma_gemm(
    const unsigned short* __restrict__ Ahi, const unsigned short* __restrict__ Alo,
    int lda, int aGrpK,
    const unsigned short* __restrict__ Bhi, const unsigned short* __restrict__ Blo,
    int ldb, int bGrp,
    const float* __restrict__ bias, int biasGrp,
    float* __restrict__ Cf, unsigned short* __restrict__ Chi, unsigned short* __restrict__ Clo,
    int ldc, long long cGrp,
    int N, int kLen, int kSplit)
{
    __shared__ __align__(16) unsigned short AsH[128 * 64];
    __shared__ __align__(16) unsigned short AsL[128 * 64];
    __shared__ __align__(16) unsigned short BsH[128 * 64];
    __shared__ __align__(16) unsigned short BsL[128 * 64];

    // XCD-aware remap: hw linear id -> logical tile id (bijective, nwg%8==0)
    const int gx = gridDim.x, gy = gridDim.y;
    const int nwg = gx * gy * gridDim.z;
    int lin = blockIdx.x + gx * (blockIdx.y + gy * blockIdx.z);
    int logical = (nwg & 7) ? lin : ((lin & 7) * (nwg >> 3) + (lin >> 3));
    const int bx = logical % gx;
    const int by = (logical / gx) % gy;
    const int z  = logical / (gx * gy);

    const int g = kSplit ? 0 : z;
    const int kStart = kSplit ? z * kLen : 0;
    const size_t aOff = (size_t)g * aGrpK;
    const size_t bOff = (size_t)g * bGrp;
    const size_t cOff = (size_t)z * cGrp;
    const int bias0 = g * biasGrp;

    const int t = threadIdx.x;
    const int rh = t >> 3;          // 0..31: row within 32-row staging stripe
    const int ch = t & 7;           // 16B chunk within 64-elem row
    const int chs = ch ^ (rh & 7);  // pre-swizzled source chunk
    const int rowBase = by * 128;
    const int colBase = bx * 128;

    const int wv = t >> 6, wm = wv >> 1, wn = wv & 1;
    const int l = t & 63, lr = l & 15, lk = l >> 4;
    const int xr = lr & 7;          // read-side XOR ((row&7) == (lr&7))

    f32x4 acc[4][4] = {};

    for (int k0 = 0; k0 < kLen; k0 += 64) {
        const size_t kk = (size_t)(kStart + k0 + chs * 8);
        const unsigned short* aSH = Ahi + aOff + (size_t)(rowBase + rh) * lda + kk;
        const unsigned short* aSL = Alo + aOff + (size_t)(rowBase + rh) * lda + kk;
        unsigned short* aDH = &AsH[rh * 64 + ch * 8];
        unsigned short* aDL = &AsL[rh * 64 + ch * 8];
        #pragma unroll
        for (int it = 0; it < 4; ++it) {
            gload16(aSH + (size_t)(32 * it) * lda, aDH + it * 2048);
            gload16(aSL + (size_t)(32 * it) * lda, aDL + it * 2048);
        }
        #pragma unroll
        for (int it = 0; it < 4; ++it) {
            int bn = colBase + rh + 32 * it; bn = bn < N ? bn : N - 1;
            size_t bo = bOff + (size_t)bn * ldb + kk;
            gload16(Bhi + bo, &BsH[(rh + 32 * it) * 64 + ch * 8]);
            gload16(Blo + bo, &BsL[(rh + 32 * it) * 64 + ch * 8]);
        }
        __syncthreads();
        #pragma unroll
        for (int s = 0; s < 2; ++s) {
            const int c = s * 4 + lk;
            const int co = (c ^ xr) * 8;
            short8 aH[4], aL[4], bH[4], bL[4];
            #pragma unroll
            for (int i = 0; i < 4; ++i) {
                int off = (wm * 64 + i * 16 + lr) * 64 + co;
                aH[i] = *(const short8*)&AsH[off];
                aL[i] = *(const short8*)&AsL[off];
            }
            #pragma unroll
            for (int j = 0; j < 4; ++j) {
                int off = (wn * 64 + j * 16 + lr) * 64 + co;
                bH[j] = *(const short8*)&BsH[off];
                bL[j] = *(const short8*)&BsL[off];
            }
            #pragma unroll
            for (int i = 0; i < 4; ++i)
                #pragma unroll
                for (int j = 0; j < 4; ++j) {
                    acc[i][j] = __builtin_amdgcn_mfma_f32_16x16x32_bf16(aH[i], bH[j], acc[i][j], 0, 0, 0);
                    acc[i][j] = __builtin_amdgcn_mfma_f32_16x16x32_bf16(aH[i], bL[j], acc[i][j], 0, 0, 0);
                    acc[i][j] = __builtin_amdgcn_mfma_f32_16x16x32_bf16(aL[i], bH[j], acc[i][j], 0, 0, 0);
                }
        }
        __syncthreads();
    }

    #pragma unroll
    for (int i = 0; i < 4; ++i) {
        #pragma unroll
        for (int j = 0; j < 4; ++j) {
            #pragma unroll
            for (int r = 0; r < 4; ++r) {
                int row = rowBase + wm * 64 + i * 16 + lk * 4 + r;
                int col = colBase + wn * 64 + j * 16 + lr;
                if (col < N) {
                    float v = acc[i][j][r];
                    if (bias) v += bias[bias0 + col];
                    if (DO_TANH) v = tanhf(v);
                    size_t off = cOff + (size_t)row * ldc + col;
                    if (OUT_SPLIT) {
                        unsigned short hh = f2bf(v);
                        Chi[off] = hh;
                        Clo[off] = f2bf(v - bf2f(hh));
                    } else {
                        Cf[off] = v;
                    }
                }
            }
        }
    }
}

// ---------------------------------------------------------------------------
// inputs split: [32768 rows][978] fp32 -> [32768][1024] bf16 hi/lo, zero-pad.
// ---------------------------------------------------------------------------
__global__ void split_rows_in(const float* __restrict__ src,
                              unsigned short* __restrict__ hi,
                              unsigned short* __restrict__ lo)
{
    int o = blockIdx.x >> 1;
    int c = ((blockIdx.x & 1) * 256 + threadIdx.x) * 2;
    const float* s = src + (size_t)o * G_;
    size_t d = (size_t)o * KP_ + c;
    float v0 = (c     < G_) ? s[c]     : 0.f;
    float v1 = (c + 1 < G_) ? s[c + 1] : 0.f;
    unsigned short h0 = f2bf(v0), h1 = f2bf(v1);
    unsigned short l0 = f2bf(v0 - bf2f(h0)), l1 = f2bf(v1 - bf2f(h1));
    *(unsigned int*)&hi[d] = (unsigned)h0 | ((unsigned)h1 << 16);
    *(unsigned int*)&lo[d] = (unsigned)l0 | ((unsigned)l1 << 16);
}

// ---------------------------------------------------------------------------
// weight transpose + split (+K pad): src fp32 [g][Ksrc][N] -> bf16 [g][N][Kdst]
// ---------------------------------------------------------------------------
__global__ void transpose_split(const float* __restrict__ src, long long sGrp,
                                unsigned short* __restrict__ hi, unsigned short* __restrict__ lo,
                                long long dGrp, int Ksrc, int Kdst, int N)
{
    __shared__ float tile[32][33];
    int g = blockIdx.z;
    int k0 = blockIdx.y * 32, n0 = blockIdx.x * 32;
    int tx = threadIdx.x & 31, ty = threadIdx.x >> 5;
    #pragma unroll
    for (int i = 0; i < 4; ++i) {
        int k = k0 + ty + 8 * i, n = n0 + tx;
        float v = 0.f;
        if (k < Ksrc && n < N) v = src[(size_t)g * sGrp + (size_t)k * N + n];
        tile[ty + 8 * i][tx] = v;
    }
    __syncthreads();
    #pragma unroll
    for (int i = 0; i < 4; ++i) {
        int n = n0 + ty + 8 * i, k = k0 + tx;
        if (n < N && k < Kdst) {
            float v = tile[tx][ty + 8 * i];
            unsigned short h = f2bf(v);
            size_t off = (size_t)g * dGrp + (size_t)n * Kdst + k;
            hi[off] = h;
            lo[off] = f2bf(v - bf2f(h));
        }
    }
}

// combine split-K partials of K2: z1 = tanh(sum_z P[z] + b1)
__global__ void combine4_tanh(const float* __restrict__ P, const float* __restrict__ b1,
                              float* __restrict__ z1)
{
    const int MN = B_ * D1_;
    int i = blockIdx.x * 256 + threadIdx.x;
    float v = P[i] + P[i + MN] + P[i + 2 * MN] + P[i + 3 * MN] + b1[i & (D1_ - 1)];
    z1[i] = tanhf(v);
}

// ---------------------------------------------------------------------------
// fp32 vector GEMM for the two tiny GEMMs K3/K5; optional split-bf16 out.
// ---------------------------------------------------------------------------
__global__ __launch_bounds__(256) void gemm_bt(
    const float* __restrict__ A, int aRow, int aGrp,
    const float* __restrict__ Bm, int bGrp,
    const float* __restrict__ bias, int biasGrp,
    float* __restrict__ C, int cRow, int cGrp,
    int M, int N, int K, int doTanh,
    unsigned short* __restrict__ Shi, unsigned short* __restrict__ Slo)
{
    __shared__ float As[16][68];
    __shared__ float Bs[16][64];

    const int g = blockIdx.z;
    const float* Ag = A  + (size_t)g * aGrp;
    const float* Bg = Bm + (size_t)g * bGrp;
    const float* bg = bias + (size_t)g * biasGrp;

    const int tid = threadIdx.x;
    const int tx = tid & 15, ty = tid >> 4;
    const int rowBase = blockIdx.y * 64;
    const int colBase = blockIdx.x * 64;

    float acc[4][4] = {};

    for (int k0 = 0; k0 < K; k0 += 16) {
        #pragma unroll
        for (int i = 0; i < 4; ++i) {
            int e = tid + 256 * i;
            int r = e >> 4, kk = e & 15;
            int kg = k0 + kk;
            float v = 0.f;
            if (kg < K) v = Ag[(size_t)(rowBase + r) * aRow + kg];
            As[kk][r] = v;
        }
        #pragma unroll
        for (int i = 0; i < 4; ++i) {
            int e = tid + 256 * i;
            int kk = e >> 6, c = e & 63;
            int kg = k0 + kk, cg = colBase + c;
            float v = 0.f;
            if (kg < K && cg < N) v = Bg[(size_t)kg * N + cg];
            Bs[kk][c] = v;
        }
        __syncthreads();
        #pragma unroll
        for (int kk = 0; kk < 16; ++kk) {
            float4 a4 = *(const float4*)&As[kk][ty * 4];
            float4 b4 = *(const float4*)&Bs[kk][tx * 4];
            float av[4] = {a4.x, a4.y, a4.z, a4.w};
            float bv[4] = {b4.x, b4.y, b4.z, b4.w};
            #pragma unroll
            for (int i = 0; i < 4; ++i)
                #pragma unroll
                for (int j = 0; j < 4; ++j)
                    acc[i][j] = fmaf(av[i], bv[j], acc[i][j]);
        }
        __syncthreads();
    }

    #pragma unroll
    for (int i = 0; i < 4; ++i) {
        int row = rowBase + ty * 4 + i;
        #pragma unroll
        for (int j = 0; j < 4; ++j) {
            int col = colBase + tx * 4 + j;
            if (col < N) {
                float v = acc[i][j] + bg[col];
                if (doTanh) v = tanhf(v);
                size_t off = (size_t)g * cGrp + (size_t)row * cRow + col;
                if (Shi) {
                    unsigned short h = f2bf(v);
                    Shi[off] = h;
                    Slo[off] = f2bf(v - bf2f(h));
                } else {
                    C[off] = v;
                }
            }
        }
    }
}

// ---------------- VQ ----------------
// prep: per-code |cb_i|^2 in f64 (+f32 copy); zero the loss accumulator.
__global__ void vq_prep(const float* __restrict__ cb, double* __restrict__ csq,
                        float* __restrict__ csqf, double* __restrict__ acc)
{
    int i = threadIdx.x;              // 512 threads, one per code
    double s = 0.0;
    for (int d = 0; d < D2_; ++d) {
        double v = (double)cb[i * D2_ + d];
        s = fma(v, v, s);
    }
    csq[i] = s;
    csqf[i] = (float)s;
    if (i == 0) *acc = 0.0;
}

// 4 rows per block. Stage 1: f32 scores (4-row ILP, codebook reuse).
// Stage 2: f64 re-score of candidates within best+MARGIN (MARGIN=1e-5 vs
// f32 score error <~4e-8), argmin with first-index tie-break — identical
// semantics to the round-2 all-f64 kernel.
__global__ __launch_bounds__(256) void vq_kernel(
    const float* __restrict__ z, const float* __restrict__ cb,
    const double* __restrict__ csq, const float* __restrict__ csqf,
    float* __restrict__ qst_out, float* __restrict__ q_ws,
    double* __restrict__ acc)
{
    __shared__ float  zsh[4][D2_];
    __shared__ float  rmin[256];
    __shared__ int    cand[64];
    __shared__ double dval[64];
    __shared__ int    ncand;
    __shared__ int    bestidx;
    __shared__ float  lsum[256];

    const int b0 = blockIdx.x * 4;
    const int t = threadIdx.x;

    ((float*)zsh)[t]       = z[(size_t)b0 * D2_ + t];
    ((float*)zsh)[t + 256] = z[(size_t)b0 * D2_ + t + 256];
    __syncthreads();

    // f32 scoring: codes t and t+256, 4 rows each
    float sc[2][4];
    #pragma unroll
    for (int ii = 0; ii < 2; ++ii) {
        int i = t + (ii << 8);
        const float4* cr = (const float4*)(cb + (size_t)i * D2_);
        float d0 = 0.f, d1 = 0.f, d2 = 0.f, d3 = 0.f;
        #pragma unroll 4
        for (int d4 = 0; d4 < 32; ++d4) {
            float4 c4 = cr[d4];
            float4 z0 = ((const float4*)zsh[0])[d4];
            float4 z1 = ((const float4*)zsh[1])[d4];
            float4 z2 = ((const float4*)zsh[2])[d4];
            float4 z3 = ((const float4*)zsh[3])[d4];
            d0 = fmaf(c4.x, z0.x, fmaf(c4.y, z0.y, fmaf(c4.z, z0.z, fmaf(c4.w, z0.w, d0))));
            d1 = fmaf(c4.x, z1.x, fmaf(c4.y, z1.y, fmaf(c4.z, z1.z, fmaf(c4.w, z1.w, d1))));
            d2 = fmaf(c4.x, z2.x, fmaf(c4.y, z2.y, fmaf(c4.z, z2.z, fmaf(c4.w, z2.w, d2))));
            d3 = fmaf(c4.x, z3.x, fmaf(c4.y, z3.y, fmaf(c4.z, z3.z, fmaf(c4.w, z3.w, d3))));
        }
        float cs = csqf[i];
        sc[ii][0] = cs - 2.f * d0;
        sc[ii][1] = cs - 2.f * d1;
        sc[ii][2] = cs - 2.f * d2;
        sc[ii][3] = cs - 2.f * d3;
    }

    float lossAcc = 0.f;
    for (int r = 0; r < 4; ++r) {
        rmin[t] = fminf(sc[0][r], sc[1][r]);
        __syncthreads();
        for (int off = 128; off > 0; off >>= 1) {
            if (t < off) rmin[t] = fminf(rmin[t], rmin[t + off]);
            __syncthreads();
        }
        float bestv = rmin[0];
        if (t == 0) ncand = 0;
        __syncthreads();
        #pragma unroll
        for (int ii = 0; ii < 2; ++ii)
            if (sc[ii][r] <= bestv + 1e-5f) {
                int p = atomicAdd(&ncand, 1);
                if (p < 64) cand[p] = t + (ii << 8);
            }
        __syncthreads();
        int nc = ncand < 64 ? ncand : 64;
        if (t < nc) {
            int i = cand[t];
            const float* cr = cb + (size_t)i * D2_;
            double dot = 0.0;
            for (int d = 0; d < D2_; ++d)
                dot = fma((double)cr[d], (double)zsh[r][d], dot);
            dval[t] = csq[i] - 2.0 * dot;
        }
        __syncthreads();
        if (t == 0) {
            double bv = 1e300; int bi = 0x7fffffff;
            for (int j2 = 0; j2 < nc; ++j2) {
                double v = dval[j2]; int i2 = cand[j2];
                if (v < bv || (v == bv && i2 < bi)) { bv = v; bi = i2; }
            }
            bestidx = bi;
        }
        __syncthreads();
        int idx = bestidx;
        if (t < D2_) {
            float qv = cb[(size_t)idx * D2_ + t];
            size_t o = (size_t)(b0 + r) * D2_ + t;
            qst_out[o] = qv;
            q_ws[o] = qv;
            float d = qv - zsh[r][t];
            lossAcc += d * d;
        }
        __syncthreads();
    }
    lsum[t] = lossAcc;
    __syncthreads();
    for (int off = 128; off > 0; off >>= 1) {
        if (t < off) lsum[t] += lsum[t + off];
        __syncthreads();
    }
    if (t == 0) atomicAdd(acc, (double)lsum[0]);
}

__global__ void finalize_loss(const double* __restrict__ acc, float* __restrict__ out0)
{
    out0[0] = (float)(1.25 * (*acc) / (double)((size_t)B_ * D2_));
}

// ---------------------------------------------------------------------------
extern "C" void kernel_launch(void* const* d_in, const int* in_sizes, int n_in,
                              void* d_out, int out_size, void* d_ws, size_t ws_size,
                              hipStream_t stream)
{
    const float* inputs = (const float*)d_in[0];
    const float* enc_w  = (const float*)d_in[1];
    const float* enc_b  = (const float*)d_in[2];
    const float* w1     = (const float*)d_in[3];
    const float* b1     = (const float*)d_in[4];
    const float* w2     = (const float*)d_in[5];
    const float* b2     = (const float*)d_in[6];
    const float* cb     = (const float*)d_in[7];
    const float* dw1    = (const float*)d_in[8];
    const float* db1    = (const float*)d_in[9];
    const float* dw2    = (const float*)d_in[10];
    const float* db2    = (const float*)d_in[11];
    const float* dec_w  = (const float*)d_in[12];
    const float* dec_b  = (const float*)d_in[13];

    float* out = (float*)d_out;
    float* x_recon = out + 1;
    float* qst     = out + 1 + (size_t)B_ * C_ * G_;

    const size_t MB = 1u << 20;
    const size_t NEED = 208 * MB;
    dim3 blk(256);

    if (ws_size >= NEED) {
        char* W = (char*)d_ws;
        unsigned short* ipad_hi = (unsigned short*)(W + 0);        // 64MB (dead after K1)
        unsigned short* ipad_lo = (unsigned short*)(W + 64 * MB);  // 64MB
        unsigned short* h_hi    = (unsigned short*)(W + 128 * MB); // 32MB
        unsigned short* h_lo    = (unsigned short*)(W + 160 * MB); // 32MB
        unsigned short* ewt_hi  = (unsigned short*)(W + 192 * MB); // 8MB
        unsigned short* ewt_lo  = (unsigned short*)(W + 200 * MB); // 8MB
        // region A reuse after K1:
        unsigned short* w1t_hi  = (unsigned short*)(W + 0);
        unsigned short* w1t_lo  = (unsigned short*)(W + 2 * MB);
        unsigned short* dw2t_hi = (unsigned short*)(W + 4 * MB);
        unsigned short* dw2t_lo = (unsigned short*)(W + 6 * MB);
        unsigned short* dwt_hi  = (unsigned short*)(W + 8 * MB);   // dec_wt 7.65MB
        unsigned short* dwt_lo  = (unsigned short*)(W + 16 * MB);
        float* partials = (float*)(W + 24 * MB);                   // 16MB
        float* z1 = (float*)(W + 40 * MB);                         // 4MB
        float* z  = (float*)(W + 44 * MB);                         // 2MB
        float* q  = (float*)(W + 46 * MB);                         // 2MB
        unsigned short* r1_hi = (unsigned short*)(W + 48 * MB);
        unsigned short* r1_lo = (unsigned short*)(W + 50 * MB);
        unsigned short* r_hi  = (unsigned short*)(W + 52 * MB);    // 32MB
        unsigned short* r_lo  = (unsigned short*)(W + 84 * MB);    // 32MB -> ends 116MB
        double* csq  = (double*)(W + 116 * MB);                    // 4KB
        double* acc  = (double*)(W + 116 * MB + 4096);
        float*  csqf = (float*)(W + 116 * MB + 4096 + 64);

        split_rows_in<<<dim3(B_ * C_ * 2), blk, 0, stream>>>(inputs, ipad_hi, ipad_lo);
        transpose_split<<<dim3(16, 32, 8), blk, 0, stream>>>(
            enc_w, (long long)G_ * D0_, ewt_hi, ewt_lo, (long long)D0_ * KP_, G_, KP_, D0_);

        // K1: h = tanh(inputs @ enc_w + enc_b), split-bf16 out
        mfma_gemm<1, 1><<<dim3(4, 32, 8), blk, 0, stream>>>(
            ipad_hi, ipad_lo, C_ * KP_, KP_,
            ewt_hi, ewt_lo, KP_, D0_ * KP_,
            enc_b, D0_,
            nullptr, h_hi, h_lo, CD_, 512LL,
            D0_, KP_, 0);

        transpose_split<<<dim3(8, 128, 1), blk, 0, stream>>>(
            w1, 0, w1t_hi, w1t_lo, 0, CD_, CD_, D1_);
        transpose_split<<<dim3(128, 8, 1), blk, 0, stream>>>(
            dw2, 0, dw2t_hi, dw2t_lo, 0, D1_, D1_, CD_);
        transpose_split<<<dim3(31, 16, 8), blk, 0, stream>>>(
            dec_w, (long long)D0_ * G_, dwt_hi, dwt_lo, (long long)G_ * D0_, D0_, D0_, G_);

        // K2: partials[z] = h @ w1 (split-K = 4)
        mfma_gemm<0, 0><<<dim3(2, 32, 4), blk, 0, stream>>>(
            h_hi, h_lo, CD_, 0,
            w1t_hi, w1t_lo, CD_, 0,
            nullptr, 0,
            partials, nullptr, nullptr, D1_, (long long)B_ * D1_,
            D1_, CD_ / 4, 1);
        combine4_tanh<<<dim3(B_ * D1_ / 256), blk, 0, stream>>>(partials, b1, z1);

        // K3: z = tanh(z1 @ w2 + b2)  (fp32)
        gemm_bt<<<dim3(2, 64, 1), blk, 0, stream>>>(
            z1, D1_, 0, w2, 0, b2, 0, z, D2_, 0, B_, D2_, D1_, 1, nullptr, nullptr);

        // VQ
        vq_prep<<<dim3(1), dim3(K_), 0, stream>>>(cb, csq, csqf, acc);
        vq_kernel<<<dim3(B_ / 4), blk, 0, stream>>>(z, cb, csq, csqf, qst, q, acc);

        // K5: r1 = tanh(q @ dw1 + db1)  (fp32, split-bf16 out)
        gemm_bt<<<dim3(4, 64, 1), blk, 0, stream>>>(
            q, D2_, 0, dw1, 0, db1, 0, nullptr, D1_, 0, B_, D1_, D2_, 1, r1_hi, r1_lo);

        // K6: r = tanh(r1 @ dw2 + db2), split-bf16 out
        mfma_gemm<1, 1><<<dim3(32, 32, 1), blk, 0, stream>>>(
            r1_hi, r1_lo, D1_, 0,
            dw2t_hi, dw2t_lo, D1_, 0,
            db2, 0,
            nullptr, r_hi, r_lo, CD_, 0LL,
            CD_, D1_, 0);

        // K7: x_recon = r @ dec_w + dec_b (grouped, fp32 out, N=978 edge)
        mfma_gemm<0, 0><<<dim3(8, 32, 8), blk, 0, stream>>>(
            r_hi, r_lo, CD_, D0_,
            dwt_hi, dwt_lo, D0_, G_ * D0_,
            dec_b, G_,
            x_recon, nullptr, nullptr, C_ * G_, (long long)G_,
            G_, D0_, 0);

        finalize_loss<<<dim3(1), dim3(1), 0, stream>>>(acc, out);
    } else {
        // -------- fallback: fp32 path --------
        float*  h   = (float*)d_ws;
        float*  z1  = h  + (size_t)B_ * CD_;
        float*  z   = z1 + (size_t)B_ * D1_;
        float*  q   = z  + (size_t)B_ * D2_;
        double* csq = (double*)(q + (size_t)B_ * D2_);
        double* acc = csq + K_;
        float*  csqf = (float*)(acc + 8);

        gemm_bt<<<dim3(D0_ / 64, B_ / 64, C_), blk, 0, stream>>>(
            inputs, C_ * G_, G_, enc_w, G_ * D0_, enc_b, D0_,
            h, CD_, D0_, B_, D0_, G_, 1, nullptr, nullptr);
        gemm_bt<<<dim3(D1_ / 64, B_ / 64, 1), blk, 0, stream>>>(
            h, CD_, 0, w1, 0, b1, 0, z1, D1_, 0, B_, D1_, CD_, 1, nullptr, nullptr);
        gemm_bt<<<dim3(D2_ / 64, B_ / 64, 1), blk, 0, stream>>>(
            z1, D1_, 0, w2, 0, b2, 0, z, D2_, 0, B_, D2_, D1_, 1, nullptr, nullptr);
        vq_prep<<<dim3(1), dim3(K_), 0, stream>>>(cb, csq, csqf, acc);
        vq_kernel<<<dim3(B_ / 4), blk, 0, stream>>>(z, cb, csq, csqf, qst, q, acc);
        gemm_bt<<<dim3(D1_ / 64, B_ / 64, 1), blk, 0, stream>>>(
            q, D2_, 0, dw1, 0, db1, 0, z1, D1_, 0, B_, D1_, D2_, 1, nullptr, nullptr);
        gemm_bt<<<dim3(CD_ / 64, B_ / 64, 1), blk, 0, stream>>>(
            z1, D1_, 0, dw2, 0, db2, 0, h, CD_, 0, B_, CD_, D1_, 1, nullptr, nullptr);
        gemm_bt<<<dim3((G_ + 63) / 64, B_ / 64, C_), blk, 0, stream>>>(
            h, CD_, D0_, dec_w, D0_ * G_, dec_b, G_,
            x_recon, C_ * G_, G_, B_, G_, D0_, 0, nullptr, nullptr);
        finalize_loss<<<dim3(1), dim3(1), 0, stream>>>(acc, out);
    }
}

// Round 4
// 526.466 us; speedup vs baseline: 4.2167x; 1.0665x over previous
//
#include <hip/hip_runtime.h>

#define B_   4096
#define C_   8
#define G_   978
#define D0_  512
#define D1_  256
#define D2_  128
#define K_   512
#define KP_  1024          // padded G (K of enc GEMM)
#define CD_  4096          // C_*D0_

typedef short short8 __attribute__((ext_vector_type(8)));
typedef float f32x4  __attribute__((ext_vector_type(4)));

// ---------------- bf16 helpers (RNE) ----------------
__device__ __forceinline__ unsigned short f2bf(float v) {
    union { float f; unsigned u; } x; x.f = v;
    unsigned r = (x.u + 0x7fffu + ((x.u >> 16) & 1u)) >> 16;
    return (unsigned short)r;
}
__device__ __forceinline__ float bf2f(unsigned short b) {
    union { unsigned u; float f; } x; x.u = ((unsigned)b) << 16;
    return x.f;
}

__device__ __forceinline__ void gload16(const unsigned short* g, unsigned short* l) {
    typedef const __attribute__((address_space(1))) unsigned int* gp_t;
    typedef __attribute__((address_space(3))) unsigned int* lp_t;
    __builtin_amdgcn_global_load_lds((gp_t)(const void*)g, (lp_t)(void*)l, 16, 0, 0);
}

// XCD-aware bijective remap (valid when nwg % 8 == 0)
__device__ __forceinline__ void xcd_remap(int& bx, int& by, int& z) {
    const int gx = gridDim.x, gy = gridDim.y;
    const int nwg = gx * gy * gridDim.z;
    int lin = blockIdx.x + gx * (blockIdx.y + gy * blockIdx.z);
    int logical = (nwg & 7) ? lin : ((lin & 7) * (nwg >> 3) + (lin >> 3));
    bx = logical % gx;
    by = (logical / gx) % gy;
    z  = logical / (gx * gy);
}

// ---------------------------------------------------------------------------
// Split-bf16 fused MFMA GEMM (encoder path): C = [tanh]((Ahi+Alo)@(Bhi+Blo)^T + bias)
// Tile 128x128, BK=32, 4 waves. Double-buffered LDS (2x4x8KB = 64KB) with
// prefetch-before-compute. XOR swizzle: chunk ^= (row&3) on both the
// pre-swizzled global source and the ds_read side (rule #21).
// ---------------------------------------------------------------------------
template<int DO_TANH, int OUT_SPLIT>
__global__ __launch_bounds__(256, 2) void mfma_split(
    const unsigned short* __restrict__ Ahi, const unsigned short* __restrict__ Alo,
    int lda, int aGrpK,
    const unsigned short* __restrict__ Bhi, const unsigned short* __restrict__ Blo,
    int ldb, int bGrp,
    const float* __restrict__ bias, int biasGrp,
    float* __restrict__ Cf, unsigned short* __restrict__ Chi, unsigned short* __restrict__ Clo,
    int ldc, long long cGrp,
    int N, int kLen, int kSplit)
{
    __shared__ __align__(16) unsigned short AsH[2][128 * 32];
    __shared__ __align__(16) unsigned short AsL[2][128 * 32];
    __shared__ __align__(16) unsigned short BsH[2][128 * 32];
    __shared__ __align__(16) unsigned short BsL[2][128 * 32];

    int bx, by, z;
    xcd_remap(bx, by, z);

    const int g = kSplit ? 0 : z;
    const int kStart = kSplit ? z * kLen : 0;
    const size_t aOff = (size_t)g * aGrpK;
    const size_t bOff = (size_t)g * bGrp;
    const size_t cOff = (size_t)z * cGrp;
    const int bias0 = g * biasGrp;

    const int t = threadIdx.x;
    const int rh = t >> 2;          // 0..63 staging row (and +64)
    const int ch = t & 3;           // 16B chunk within 32-elem row
    const int chs = ch ^ (rh & 3);  // pre-swizzled source chunk
    const int rowBase = by * 128;
    const int colBase = bx * 128;

    const int wv = t >> 6, wm = wv >> 1, wn = wv & 1;
    const int l = t & 63, lr = l & 15, lk = l >> 4;
    const int xr = lr & 3;          // read-side XOR key

    f32x4 acc[4][4] = {};

    const int nsteps = kLen >> 5;   // kLen multiple of 32 (1024 here)

    // ---- stage one K-step into buffer `buf` at k-offset kAbs ----
    auto stage = [&](int buf, int kAbs) {
        const size_t kk = (size_t)(kAbs + chs * 8);
        #pragma unroll
        for (int it = 0; it < 2; ++it) {
            int ar = rowBase + rh + 64 * it;
            size_t ao = aOff + (size_t)ar * lda + kk;
            int dst = (rh + 64 * it) * 32 + ch * 8;
            gload16(Ahi + ao, &AsH[buf][dst]);
            gload16(Alo + ao, &AsL[buf][dst]);
            int bn = colBase + rh + 64 * it; bn = bn < N ? bn : N - 1;
            size_t bo = bOff + (size_t)bn * ldb + kk;
            gload16(Bhi + bo, &BsH[buf][dst]);
            gload16(Blo + bo, &BsL[buf][dst]);
        }
    };

    stage(0, kStart);

    for (int s = 0; s < nsteps; ++s) {
        const int cur = s & 1;
        __syncthreads();                         // drains vmcnt: buf cur ready
        if (s + 1 < nsteps) stage(cur ^ 1, kStart + (s + 1) * 32);

        short8 aH[4], aL[4], bH[4], bL[4];
        #pragma unroll
        for (int i = 0; i < 4; ++i) {
            int off = (wm * 64 + i * 16 + lr) * 32 + (lk ^ xr) * 8;
            aH[i] = *(const short8*)&AsH[cur][off];
            aL[i] = *(const short8*)&AsL[cur][off];
        }
        #pragma unroll
        for (int j = 0; j < 4; ++j) {
            int off = (wn * 64 + j * 16 + lr) * 32 + (lk ^ xr) * 8;
            bH[j] = *(const short8*)&BsH[cur][off];
            bL[j] = *(const short8*)&BsL[cur][off];
        }
        #pragma unroll
        for (int i = 0; i < 4; ++i)
            #pragma unroll
            for (int j = 0; j < 4; ++j) {
                acc[i][j] = __builtin_amdgcn_mfma_f32_16x16x32_bf16(aH[i], bH[j], acc[i][j], 0, 0, 0);
                acc[i][j] = __builtin_amdgcn_mfma_f32_16x16x32_bf16(aH[i], bL[j], acc[i][j], 0, 0, 0);
                acc[i][j] = __builtin_amdgcn_mfma_f32_16x16x32_bf16(aL[i], bH[j], acc[i][j], 0, 0, 0);
            }
    }

    #pragma unroll
    for (int i = 0; i < 4; ++i)
        #pragma unroll
        for (int j = 0; j < 4; ++j)
            #pragma unroll
            for (int r = 0; r < 4; ++r) {
                int row = rowBase + wm * 64 + i * 16 + lk * 4 + r;
                int col = colBase + wn * 64 + j * 16 + lr;
                if (col < N) {
                    float v = acc[i][j][r];
                    if (bias) v += bias[bias0 + col];
                    if (DO_TANH) v = tanhf(v);
                    size_t off = cOff + (size_t)row * ldc + col;
                    if (OUT_SPLIT) {
                        unsigned short hh = f2bf(v);
                        Chi[off] = hh;
                        Clo[off] = f2bf(v - bf2f(hh));
                    } else {
                        Cf[off] = v;
                    }
                }
            }
}

// ---------------------------------------------------------------------------
// Pure-bf16 MFMA GEMM (decoder path): C = [tanh](A @ B^T + bias)
// Tile 128x128, BK=64, double-buffered (2x2x16KB = 64KB), prefetch overlap,
// (row&7) chunk-XOR swizzle.
// ---------------------------------------------------------------------------
template<int DO_TANH, int OUT_BF>
__global__ __launch_bounds__(256, 2) void mfma_bf(
    const unsigned short* __restrict__ A, int lda, int aGrpK,
    const unsigned short* __restrict__ Bm, int ldb, long long bGrp,
    const float* __restrict__ bias, int biasGrp,
    float* __restrict__ Cf, unsigned short* __restrict__ Cbf,
    int ldc, long long cGrp,
    int N, int kLen)
{
    __shared__ __align__(16) unsigned short As[2][128 * 64];
    __shared__ __align__(16) unsigned short Bs[2][128 * 64];

    int bx, by, z;
    xcd_remap(bx, by, z);

    const size_t aOff = (size_t)z * aGrpK;
    const size_t bOff = (size_t)z * bGrp;
    const size_t cOff = (size_t)z * cGrp;
    const int bias0 = z * biasGrp;

    const int t = threadIdx.x;
    const int rh = t >> 3;          // 0..31
    const int ch = t & 7;
    const int chs = ch ^ (rh & 7);
    const int rowBase = by * 128;
    const int colBase = bx * 128;

    const int wv = t >> 6, wm = wv >> 1, wn = wv & 1;
    const int l = t & 63, lr = l & 15, lk = l >> 4;
    const int xr = lr & 7;

    f32x4 acc[4][4] = {};
    const int nsteps = kLen >> 6;

    auto stage = [&](int buf, int kAbs) {
        const size_t kk = (size_t)(kAbs + chs * 8);
        #pragma unroll
        for (int it = 0; it < 4; ++it) {
            int ar = rowBase + rh + 32 * it;
            gload16(A + aOff + (size_t)ar * lda + kk, &As[buf][(rh + 32 * it) * 64 + ch * 8]);
            int bn = colBase + rh + 32 * it; bn = bn < N ? bn : N - 1;
            gload16(Bm + bOff + (size_t)bn * ldb + kk, &Bs[buf][(rh + 32 * it) * 64 + ch * 8]);
        }
    };

    stage(0, 0);

    for (int s = 0; s < nsteps; ++s) {
        const int cur = s & 1;
        __syncthreads();
        if (s + 1 < nsteps) stage(cur ^ 1, (s + 1) * 64);
        #pragma unroll
        for (int hh = 0; hh < 2; ++hh) {
            const int co = ((hh * 4 + lk) ^ xr) * 8;
            short8 af[4], bf[4];
            #pragma unroll
            for (int i = 0; i < 4; ++i)
                af[i] = *(const short8*)&As[cur][(wm * 64 + i * 16 + lr) * 64 + co];
            #pragma unroll
            for (int j = 0; j < 4; ++j)
                bf[j] = *(const short8*)&Bs[cur][(wn * 64 + j * 16 + lr) * 64 + co];
            #pragma unroll
            for (int i = 0; i < 4; ++i)
                #pragma unroll
                for (int j = 0; j < 4; ++j)
                    acc[i][j] = __builtin_amdgcn_mfma_f32_16x16x32_bf16(af[i], bf[j], acc[i][j], 0, 0, 0);
        }
    }

    #pragma unroll
    for (int i = 0; i < 4; ++i)
        #pragma unroll
        for (int j = 0; j < 4; ++j)
            #pragma unroll
            for (int r = 0; r < 4; ++r) {
                int row = rowBase + wm * 64 + i * 16 + lk * 4 + r;
                int col = colBase + wn * 64 + j * 16 + lr;
                if (col < N) {
                    float v = acc[i][j][r];
                    if (bias) v += bias[bias0 + col];
                    if (DO_TANH) v = tanhf(v);
                    size_t off = cOff + (size_t)row * ldc + col;
                    if (OUT_BF) Cbf[off] = f2bf(v);
                    else        Cf[off] = v;
                }
            }
}

// ---------------------------------------------------------------------------
// inputs split: [32768 rows][978] fp32 -> [32768][1024] bf16 hi/lo, zero-pad.
// ---------------------------------------------------------------------------
__global__ void split_rows_in(const float* __restrict__ src,
                              unsigned short* __restrict__ hi,
                              unsigned short* __restrict__ lo)
{
    int o = blockIdx.x >> 1;
    int c = ((blockIdx.x & 1) * 256 + threadIdx.x) * 2;
    const float* s = src + (size_t)o * G_;
    size_t d = (size_t)o * KP_ + c;
    float v0 = (c     < G_) ? s[c]     : 0.f;
    float v1 = (c + 1 < G_) ? s[c + 1] : 0.f;
    unsigned short h0 = f2bf(v0), h1 = f2bf(v1);
    unsigned short l0 = f2bf(v0 - bf2f(h0)), l1 = f2bf(v1 - bf2f(h1));
    *(unsigned int*)&hi[d] = (unsigned)h0 | ((unsigned)h1 << 16);
    *(unsigned int*)&lo[d] = (unsigned)l0 | ((unsigned)l1 << 16);
}

// ---------------------------------------------------------------------------
// weight transpose + split (+K pad): src fp32 [g][Ksrc][N] -> bf16 [g][N][Kdst]
// lo == nullptr -> hi-only (plain bf16).
// ---------------------------------------------------------------------------
__global__ void transpose_split(const float* __restrict__ src, long long sGrp,
                                unsigned short* __restrict__ hi, unsigned short* __restrict__ lo,
                                long long dGrp, int Ksrc, int Kdst, int N)
{
    __shared__ float tile[32][33];
    int g = blockIdx.z;
    int k0 = blockIdx.y * 32, n0 = blockIdx.x * 32;
    int tx = threadIdx.x & 31, ty = threadIdx.x >> 5;
    #pragma unroll
    for (int i = 0; i < 4; ++i) {
        int k = k0 + ty + 8 * i, n = n0 + tx;
        float v = 0.f;
        if (k < Ksrc && n < N) v = src[(size_t)g * sGrp + (size_t)k * N + n];
        tile[ty + 8 * i][tx] = v;
    }
    __syncthreads();
    #pragma unroll
    for (int i = 0; i < 4; ++i) {
        int n = n0 + ty + 8 * i, k = k0 + tx;
        if (n < N && k < Kdst) {
            float v = tile[tx][ty + 8 * i];
            unsigned short h = f2bf(v);
            size_t off = (size_t)g * dGrp + (size_t)n * Kdst + k;
            hi[off] = h;
            if (lo) lo[off] = f2bf(v - bf2f(h));
        }
    }
}

// combine split-K partials of K2: z1 = tanh(sum_z P[z] + b1)
__global__ void combine4_tanh(const float* __restrict__ P, const float* __restrict__ b1,
                              float* __restrict__ z1)
{
    const int MN = B_ * D1_;
    int i = blockIdx.x * 256 + threadIdx.x;
    float v = P[i] + P[i + MN] + P[i + 2 * MN] + P[i + 3 * MN] + b1[i & (D1_ - 1)];
    z1[i] = tanhf(v);
}

// ---------------------------------------------------------------------------
// fp32 vector GEMM for the tiny GEMMs K3/K5; optional bf16 out (Shi).
// ---------------------------------------------------------------------------
__global__ __launch_bounds__(256) void gemm_bt(
    const float* __restrict__ A, int aRow, int aGrp,
    const float* __restrict__ Bm, int bGrp,
    const float* __restrict__ bias, int biasGrp,
    float* __restrict__ C, int cRow, int cGrp,
    int M, int N, int K, int doTanh,
    unsigned short* __restrict__ Shi)
{
    __shared__ float As[16][68];
    __shared__ float Bs[16][64];

    const int g = blockIdx.z;
    const float* Ag = A  + (size_t)g * aGrp;
    const float* Bg = Bm + (size_t)g * bGrp;
    const float* bg = bias + (size_t)g * biasGrp;

    const int tid = threadIdx.x;
    const int tx = tid & 15, ty = tid >> 4;
    const int rowBase = blockIdx.y * 64;
    const int colBase = blockIdx.x * 64;

    float acc[4][4] = {};

    for (int k0 = 0; k0 < K; k0 += 16) {
        #pragma unroll
        for (int i = 0; i < 4; ++i) {
            int e = tid + 256 * i;
            int r = e >> 4, kk = e & 15;
            int kg = k0 + kk;
            float v = 0.f;
            if (kg < K) v = Ag[(size_t)(rowBase + r) * aRow + kg];
            As[kk][r] = v;
        }
        #pragma unroll
        for (int i = 0; i < 4; ++i) {
            int e = tid + 256 * i;
            int kk = e >> 6, c = e & 63;
            int kg = k0 + kk, cg = colBase + c;
            float v = 0.f;
            if (kg < K && cg < N) v = Bg[(size_t)kg * N + cg];
            Bs[kk][c] = v;
        }
        __syncthreads();
        #pragma unroll
        for (int kk = 0; kk < 16; ++kk) {
            float4 a4 = *(const float4*)&As[kk][ty * 4];
            float4 b4 = *(const float4*)&Bs[kk][tx * 4];
            float av[4] = {a4.x, a4.y, a4.z, a4.w};
            float bv[4] = {b4.x, b4.y, b4.z, b4.w};
            #pragma unroll
            for (int i = 0; i < 4; ++i)
                #pragma unroll
                for (int j = 0; j < 4; ++j)
                    acc[i][j] = fmaf(av[i], bv[j], acc[i][j]);
        }
        __syncthreads();
    }

    #pragma unroll
    for (int i = 0; i < 4; ++i) {
        int row = rowBase + ty * 4 + i;
        #pragma unroll
        for (int j = 0; j < 4; ++j) {
            int col = colBase + tx * 4 + j;
            if (col < N) {
                float v = acc[i][j] + bg[col];
                if (doTanh) v = tanhf(v);
                size_t off = (size_t)g * cGrp + (size_t)row * cRow + col;
                if (Shi) Shi[off] = f2bf(v);
                else     C[off] = v;
            }
        }
    }
}

// ---------------- VQ ----------------
__global__ void vq_prep(const float* __restrict__ cb, double* __restrict__ csq,
                        float* __restrict__ csqf, double* __restrict__ acc)
{
    int i = threadIdx.x;
    double s = 0.0;
    for (int d = 0; d < D2_; ++d) {
        double v = (double)cb[i * D2_ + d];
        s = fma(v, v, s);
    }
    csq[i] = s;
    csqf[i] = (float)s;
    if (i == 0) *acc = 0.0;
}

// f32 prescore (4 rows/block) + f64 re-score of margin candidates; semantics
// identical to all-f64 argmin with first-index tie-break.
__global__ __launch_bounds__(256) void vq_kernel(
    const float* __restrict__ z, const float* __restrict__ cb,
    const double* __restrict__ csq, const float* __restrict__ csqf,
    float* __restrict__ qst_out, float* __restrict__ q_ws,
    double* __restrict__ acc)
{
    __shared__ float  zsh[4][D2_];
    __shared__ float  rmin[256];
    __shared__ int    cand[64];
    __shared__ double dval[64];
    __shared__ int    ncand;
    __shared__ int    bestidx;
    __shared__ float  lsum[256];

    const int b0 = blockIdx.x * 4;
    const int t = threadIdx.x;

    ((float*)zsh)[t]       = z[(size_t)b0 * D2_ + t];
    ((float*)zsh)[t + 256] = z[(size_t)b0 * D2_ + t + 256];
    __syncthreads();

    float sc[2][4];
    #pragma unroll
    for (int ii = 0; ii < 2; ++ii) {
        int i = t + (ii << 8);
        const float4* cr = (const float4*)(cb + (size_t)i * D2_);
        float d0 = 0.f, d1 = 0.f, d2 = 0.f, d3 = 0.f;
        #pragma unroll 4
        for (int d4 = 0; d4 < 32; ++d4) {
            float4 c4 = cr[d4];
            float4 z0 = ((const float4*)zsh[0])[d4];
            float4 z1 = ((const float4*)zsh[1])[d4];
            float4 z2 = ((const float4*)zsh[2])[d4];
            float4 z3 = ((const float4*)zsh[3])[d4];
            d0 = fmaf(c4.x, z0.x, fmaf(c4.y, z0.y, fmaf(c4.z, z0.z, fmaf(c4.w, z0.w, d0))));
            d1 = fmaf(c4.x, z1.x, fmaf(c4.y, z1.y, fmaf(c4.z, z1.z, fmaf(c4.w, z1.w, d1))));
            d2 = fmaf(c4.x, z2.x, fmaf(c4.y, z2.y, fmaf(c4.z, z2.z, fmaf(c4.w, z2.w, d2))));
            d3 = fmaf(c4.x, z3.x, fmaf(c4.y, z3.y, fmaf(c4.z, z3.z, fmaf(c4.w, z3.w, d3))));
        }
        float cs = csqf[i];
        sc[ii][0] = cs - 2.f * d0;
        sc[ii][1] = cs - 2.f * d1;
        sc[ii][2] = cs - 2.f * d2;
        sc[ii][3] = cs - 2.f * d3;
    }

    float lossAcc = 0.f;
    for (int r = 0; r < 4; ++r) {
        rmin[t] = fminf(sc[0][r], sc[1][r]);
        __syncthreads();
        for (int off = 128; off > 0; off >>= 1) {
            if (t < off) rmin[t] = fminf(rmin[t], rmin[t + off]);
            __syncthreads();
        }
        float bestv = rmin[0];
        if (t == 0) ncand = 0;
        __syncthreads();
        #pragma unroll
        for (int ii = 0; ii < 2; ++ii)
            if (sc[ii][r] <= bestv + 1e-5f) {
                int p = atomicAdd(&ncand, 1);
                if (p < 64) cand[p] = t + (ii << 8);
            }
        __syncthreads();
        int nc = ncand < 64 ? ncand : 64;
        if (t < nc) {
            int i = cand[t];
            const float* cr = cb + (size_t)i * D2_;
            double dot = 0.0;
            for (int d = 0; d < D2_; ++d)
                dot = fma((double)cr[d], (double)zsh[r][d], dot);
            dval[t] = csq[i] - 2.0 * dot;
        }
        __syncthreads();
        if (t == 0) {
            double bv = 1e300; int bi = 0x7fffffff;
            for (int j2 = 0; j2 < nc; ++j2) {
                double v = dval[j2]; int i2 = cand[j2];
                if (v < bv || (v == bv && i2 < bi)) { bv = v; bi = i2; }
            }
            bestidx = bi;
        }
        __syncthreads();
        int idx = bestidx;
        if (t < D2_) {
            float qv = cb[(size_t)idx * D2_ + t];
            size_t o = (size_t)(b0 + r) * D2_ + t;
            qst_out[o] = qv;
            q_ws[o] = qv;
            float d = qv - zsh[r][t];
            lossAcc += d * d;
        }
        __syncthreads();
    }
    lsum[t] = lossAcc;
    __syncthreads();
    for (int off = 128; off > 0; off >>= 1) {
        if (t < off) lsum[t] += lsum[t + off];
        __syncthreads();
    }
    if (t == 0) atomicAdd(acc, (double)lsum[0]);
}

__global__ void finalize_loss(const double* __restrict__ acc, float* __restrict__ out0)
{
    out0[0] = (float)(1.25 * (*acc) / (double)((size_t)B_ * D2_));
}

// ---------------------------------------------------------------------------
extern "C" void kernel_launch(void* const* d_in, const int* in_sizes, int n_in,
                              void* d_out, int out_size, void* d_ws, size_t ws_size,
                              hipStream_t stream)
{
    const float* inputs = (const float*)d_in[0];
    const float* enc_w  = (const float*)d_in[1];
    const float* enc_b  = (const float*)d_in[2];
    const float* w1     = (const float*)d_in[3];
    const float* b1     = (const float*)d_in[4];
    const float* w2     = (const float*)d_in[5];
    const float* b2     = (const float*)d_in[6];
    const float* cb     = (const float*)d_in[7];
    const float* dw1    = (const float*)d_in[8];
    const float* db1    = (const float*)d_in[9];
    const float* dw2    = (const float*)d_in[10];
    const float* db2    = (const float*)d_in[11];
    const float* dec_w  = (const float*)d_in[12];
    const float* dec_b  = (const float*)d_in[13];

    float* out = (float*)d_out;
    float* x_recon = out + 1;
    float* qst     = out + 1 + (size_t)B_ * C_ * G_;

    const size_t MB = 1u << 20;
    const size_t NEED = 208 * MB;
    dim3 blk(256);

    if (ws_size >= NEED) {
        char* W = (char*)d_ws;
        unsigned short* ipad_hi = (unsigned short*)(W + 0);        // 64MB (dead after K1)
        unsigned short* ipad_lo = (unsigned short*)(W + 64 * MB);  // 64MB
        unsigned short* h_hi    = (unsigned short*)(W + 128 * MB); // 32MB
        unsigned short* h_lo    = (unsigned short*)(W + 160 * MB); // 32MB
        unsigned short* ewt_hi  = (unsigned short*)(W + 192 * MB); // 8MB
        unsigned short* ewt_lo  = (unsigned short*)(W + 200 * MB); // 8MB
        // region A reuse after K1:
        unsigned short* w1t_hi  = (unsigned short*)(W + 0);        // 2MB
        unsigned short* w1t_lo  = (unsigned short*)(W + 2 * MB);   // 2MB
        unsigned short* dw2t    = (unsigned short*)(W + 4 * MB);   // 2MB (bf16 only)
        unsigned short* dwt     = (unsigned short*)(W + 6 * MB);   // 7.65MB (bf16 only)
        float* partials = (float*)(W + 16 * MB);                   // 16MB
        float* z1 = (float*)(W + 32 * MB);                         // 4MB
        float* z  = (float*)(W + 36 * MB);                         // 2MB
        float* q  = (float*)(W + 38 * MB);                         // 2MB
        unsigned short* r1_bf = (unsigned short*)(W + 40 * MB);    // 2MB
        unsigned short* r_bf  = (unsigned short*)(W + 42 * MB);    // 32MB -> ends 74MB
        double* csq  = (double*)(W + 74 * MB);                     // 4KB
        double* acc  = (double*)(W + 74 * MB + 4096);
        float*  csqf = (float*)(W + 74 * MB + 4096 + 64);

        split_rows_in<<<dim3(B_ * C_ * 2), blk, 0, stream>>>(inputs, ipad_hi, ipad_lo);
        transpose_split<<<dim3(16, 32, 8), blk, 0, stream>>>(
            enc_w, (long long)G_ * D0_, ewt_hi, ewt_lo, (long long)D0_ * KP_, G_, KP_, D0_);

        // K1: h = tanh(inputs @ enc_w + enc_b), split-bf16 out
        mfma_split<1, 1><<<dim3(4, 32, 8), blk, 0, stream>>>(
            ipad_hi, ipad_lo, C_ * KP_, KP_,
            ewt_hi, ewt_lo, KP_, D0_ * KP_,
            enc_b, D0_,
            nullptr, h_hi, h_lo, CD_, 512LL,
            D0_, KP_, 0);

        transpose_split<<<dim3(8, 128, 1), blk, 0, stream>>>(
            w1, 0, w1t_hi, w1t_lo, 0, CD_, CD_, D1_);
        transpose_split<<<dim3(128, 8, 1), blk, 0, stream>>>(
            dw2, 0, dw2t, nullptr, 0, D1_, D1_, CD_);
        transpose_split<<<dim3(31, 16, 8), blk, 0, stream>>>(
            dec_w, (long long)D0_ * G_, dwt, nullptr, (long long)G_ * D0_, D0_, D0_, G_);

        // K2: partials[z] = h @ w1 (split-K = 4)
        mfma_split<0, 0><<<dim3(2, 32, 4), blk, 0, stream>>>(
            h_hi, h_lo, CD_, 0,
            w1t_hi, w1t_lo, CD_, 0,
            nullptr, 0,
            partials, nullptr, nullptr, D1_, (long long)B_ * D1_,
            D1_, CD_ / 4, 1);
        combine4_tanh<<<dim3(B_ * D1_ / 256), blk, 0, stream>>>(partials, b1, z1);

        // K3: z = tanh(z1 @ w2 + b2)  (fp32)
        gemm_bt<<<dim3(2, 64, 1), blk, 0, stream>>>(
            z1, D1_, 0, w2, 0, b2, 0, z, D2_, 0, B_, D2_, D1_, 1, nullptr);

        // VQ
        vq_prep<<<dim3(1), dim3(K_), 0, stream>>>(cb, csq, csqf, acc);
        vq_kernel<<<dim3(B_ / 4), blk, 0, stream>>>(z, cb, csq, csqf, qst, q, acc);

        // K5: r1 = tanh(q @ dw1 + db1)  (fp32 compute, bf16 out)
        gemm_bt<<<dim3(4, 64, 1), blk, 0, stream>>>(
            q, D2_, 0, dw1, 0, db1, 0, nullptr, D1_, 0, B_, D1_, D2_, 1, r1_bf);

        // K6: r = tanh(r1 @ dw2 + db2), pure bf16
        mfma_bf<1, 1><<<dim3(32, 32, 1), blk, 0, stream>>>(
            r1_bf, D1_, 0,
            dw2t, D1_, 0,
            db2, 0,
            nullptr, r_bf, CD_, 0LL,
            CD_, D1_);

        // K7: x_recon = r @ dec_w + dec_b (grouped, pure bf16, fp32 out)
        mfma_bf<0, 0><<<dim3(8, 32, 8), blk, 0, stream>>>(
            r_bf, CD_, 512,
            dwt, D0_, (long long)G_ * D0_,
            dec_b, G_,
            x_recon, nullptr, C_ * G_, (long long)G_,
            G_, D0_);

        finalize_loss<<<dim3(1), dim3(1), 0, stream>>>(acc, out);
    } else {
        // -------- fallback: fp32 path --------
        float*  h   = (float*)d_ws;
        float*  z1  = h  + (size_t)B_ * CD_;
        float*  z   = z1 + (size_t)B_ * D1_;
        float*  q   = z  + (size_t)B_ * D2_;
        double* csq = (double*)(q + (size_t)B_ * D2_);
        double* acc = csq + K_;
        float*  csqf = (float*)(acc + 8);

        gemm_bt<<<dim3(D0_ / 64, B_ / 64, C_), blk, 0, stream>>>(
            inputs, C_ * G_, G_, enc_w, G_ * D0_, enc_b, D0_,
            h, CD_, D0_, B_, D0_, G_, 1, nullptr);
        gemm_bt<<<dim3(D1_ / 64, B_ / 64, 1), blk, 0, stream>>>(
            h, CD_, 0, w1, 0, b1, 0, z1, D1_, 0, B_, D1_, CD_, 1, nullptr);
        gemm_bt<<<dim3(D2_ / 64, B_ / 64, 1), blk, 0, stream>>>(
            z1, D1_, 0, w2, 0, b2, 0, z, D2_, 0, B_, D2_, D1_, 1, nullptr);
        vq_prep<<<dim3(1), dim3(K_), 0, stream>>>(cb, csq, csqf, acc);
        vq_kernel<<<dim3(B_ / 4), blk, 0, stream>>>(z, cb, csq, csqf, qst, q, acc);
        gemm_bt<<<dim3(D1_ / 64, B_ / 64, 1), blk, 0, stream>>>(
            q, D2_, 0, dw1, 0, db1, 0, z1, D1_, 0, B_, D1_, D2_, 1, nullptr);
        gemm_bt<<<dim3(CD_ / 64, B_ / 64, 1), blk, 0, stream>>>(
            z1, D1_, 0, dw2, 0, db2, 0, h, CD_, 0, B_, CD_, D1_, 1, nullptr);
        gemm_bt<<<dim3((G_ + 63) / 64, B_ / 64, C_), blk, 0, stream>>>(
            h, CD_, D0_, dec_w, D0_ * G_, dec_b, G_,
            x_recon, C_ * G_, G_, B_, G_, D0_, 0, nullptr);
        finalize_loss<<<dim3(1), dim3(1), 0, stream>>>(acc, out);
    }
}

// Round 5
// 510.722 us; speedup vs baseline: 4.3467x; 1.0308x over previous
//
#include <hip/hip_runtime.h>

#define B_   4096
#define C_   8
#define G_   978
#define D0_  512
#define D1_  256
#define D2_  128
#define K_   512
#define KP_  1024          // padded G (K of enc GEMM)
#define CD_  4096          // C_*D0_

typedef short short8 __attribute__((ext_vector_type(8)));
typedef float f32x4  __attribute__((ext_vector_type(4)));

// ---------------- bf16 helpers (RNE) ----------------
__device__ __forceinline__ unsigned short f2bf(float v) {
    union { float f; unsigned u; } x; x.f = v;
    unsigned r = (x.u + 0x7fffu + ((x.u >> 16) & 1u)) >> 16;
    return (unsigned short)r;
}
__device__ __forceinline__ float bf2f(unsigned short b) {
    union { unsigned u; float f; } x; x.u = ((unsigned)b) << 16;
    return x.f;
}

__device__ __forceinline__ void gload16(const unsigned short* g, unsigned short* l) {
    typedef const __attribute__((address_space(1))) unsigned int* gp_t;
    typedef __attribute__((address_space(3))) unsigned int* lp_t;
    __builtin_amdgcn_global_load_lds((gp_t)(const void*)g, (lp_t)(void*)l, 16, 0, 0);
}

// XCD-aware bijective remap (valid when nwg % 8 == 0)
__device__ __forceinline__ void xcd_remap(int& bx, int& by, int& z) {
    const int gx = gridDim.x, gy = gridDim.y;
    const int nwg = gx * gy * gridDim.z;
    int lin = blockIdx.x + gx * (blockIdx.y + gy * blockIdx.z);
    int logical = (nwg & 7) ? lin : ((lin & 7) * (nwg >> 3) + (lin >> 3));
    bx = logical % gx;
    by = (logical / gx) % gy;
    z  = logical / (gx * gy);
}

// ---------------------------------------------------------------------------
// Split-bf16 fused MFMA GEMM (encoder path): C = [tanh]((Ahi+Alo)@(Bhi+Blo)^T + bias)
// Tile 128x128, BK=32, 4 waves. Double-buffered LDS (2x4x8KB = 64KB) with
// prefetch-before-compute. XOR swizzle key = (row>>1)&3 on BOTH the
// pre-swizzled global source and the ds_read side (rule #21): per 16-lane
// quarter-wave this gives exactly 2 lanes per 4-bank group (free, m136).
// ---------------------------------------------------------------------------
template<int DO_TANH, int OUT_SPLIT>
__global__ __launch_bounds__(256, 2) void mfma_split(
    const unsigned short* __restrict__ Ahi, const unsigned short* __restrict__ Alo,
    int lda, int aGrpK,
    const unsigned short* __restrict__ Bhi, const unsigned short* __restrict__ Blo,
    int ldb, int bGrp,
    const float* __restrict__ bias, int biasGrp,
    float* __restrict__ Cf, unsigned short* __restrict__ Chi, unsigned short* __restrict__ Clo,
    int ldc, long long cGrp,
    int N, int kLen, int kSplit)
{
    __shared__ __align__(16) unsigned short AsH[2][128 * 32];
    __shared__ __align__(16) unsigned short AsL[2][128 * 32];
    __shared__ __align__(16) unsigned short BsH[2][128 * 32];
    __shared__ __align__(16) unsigned short BsL[2][128 * 32];

    int bx, by, z;
    xcd_remap(bx, by, z);

    const int g = kSplit ? 0 : z;
    const int kStart = kSplit ? z * kLen : 0;
    const size_t aOff = (size_t)g * aGrpK;
    const size_t bOff = (size_t)g * bGrp;
    const size_t cOff = (size_t)z * cGrp;
    const int bias0 = g * biasGrp;

    const int t = threadIdx.x;
    const int rh = t >> 2;              // 0..63 staging row (and +64)
    const int ch = t & 3;               // 16B chunk within 32-elem row
    const int chs = ch ^ ((rh >> 1) & 3);  // pre-swizzled source chunk
    const int rowBase = by * 128;
    const int colBase = bx * 128;

    const int wv = t >> 6, wm = wv >> 1, wn = wv & 1;
    const int l = t & 63, lr = l & 15, lk = l >> 4;
    const int xr = (lr >> 1) & 3;       // read-side XOR key ((row>>1)&3)

    f32x4 acc[4][4] = {};

    const int nsteps = kLen >> 5;       // kLen multiple of 32

    auto stage = [&](int buf, int kAbs) {
        const size_t kk = (size_t)(kAbs + chs * 8);
        #pragma unroll
        for (int it = 0; it < 2; ++it) {
            int ar = rowBase + rh + 64 * it;
            size_t ao = aOff + (size_t)ar * lda + kk;
            int dst = (rh + 64 * it) * 32 + ch * 8;
            gload16(Ahi + ao, &AsH[buf][dst]);
            gload16(Alo + ao, &AsL[buf][dst]);
            int bn = colBase + rh + 64 * it; bn = bn < N ? bn : N - 1;
            size_t bo = bOff + (size_t)bn * ldb + kk;
            gload16(Bhi + bo, &BsH[buf][dst]);
            gload16(Blo + bo, &BsL[buf][dst]);
        }
    };

    stage(0, kStart);

    for (int s = 0; s < nsteps; ++s) {
        const int cur = s & 1;
        __syncthreads();                         // drains vmcnt: buf cur ready
        if (s + 1 < nsteps) stage(cur ^ 1, kStart + (s + 1) * 32);

        short8 aH[4], aL[4], bH[4], bL[4];
        #pragma unroll
        for (int i = 0; i < 4; ++i) {
            int off = (wm * 64 + i * 16 + lr) * 32 + (lk ^ xr) * 8;
            aH[i] = *(const short8*)&AsH[cur][off];
            aL[i] = *(const short8*)&AsL[cur][off];
        }
        #pragma unroll
        for (int j = 0; j < 4; ++j) {
            int off = (wn * 64 + j * 16 + lr) * 32 + (lk ^ xr) * 8;
            bH[j] = *(const short8*)&BsH[cur][off];
            bL[j] = *(const short8*)&BsL[cur][off];
        }
        #pragma unroll
        for (int i = 0; i < 4; ++i)
            #pragma unroll
            for (int j = 0; j < 4; ++j) {
                acc[i][j] = __builtin_amdgcn_mfma_f32_16x16x32_bf16(aH[i], bH[j], acc[i][j], 0, 0, 0);
                acc[i][j] = __builtin_amdgcn_mfma_f32_16x16x32_bf16(aH[i], bL[j], acc[i][j], 0, 0, 0);
                acc[i][j] = __builtin_amdgcn_mfma_f32_16x16x32_bf16(aL[i], bH[j], acc[i][j], 0, 0, 0);
            }
    }

    #pragma unroll
    for (int i = 0; i < 4; ++i)
        #pragma unroll
        for (int j = 0; j < 4; ++j)
            #pragma unroll
            for (int r = 0; r < 4; ++r) {
                int row = rowBase + wm * 64 + i * 16 + lk * 4 + r;
                int col = colBase + wn * 64 + j * 16 + lr;
                if (col < N) {
                    float v = acc[i][j][r];
                    if (bias) v += bias[bias0 + col];
                    if (DO_TANH) v = tanhf(v);
                    size_t off = cOff + (size_t)row * ldc + col;
                    if (OUT_SPLIT) {
                        unsigned short hh = f2bf(v);
                        Chi[off] = hh;
                        Clo[off] = f2bf(v - bf2f(hh));
                    } else {
                        Cf[off] = v;
                    }
                }
            }
}

// ---------------------------------------------------------------------------
// Pure-bf16 MFMA GEMM (decoder path): C = [tanh](A @ B^T + bias)
// Tile 128x128, BK=64, double-buffered (2x2x16KB = 64KB), prefetch overlap,
// (row&7) chunk-XOR swizzle (128B rows: conflict-free, verified round 3).
// ---------------------------------------------------------------------------
template<int DO_TANH, int OUT_BF>
__global__ __launch_bounds__(256, 2) void mfma_bf(
    const unsigned short* __restrict__ A, int lda, int aGrpK,
    const unsigned short* __restrict__ Bm, int ldb, long long bGrp,
    const float* __restrict__ bias, int biasGrp,
    float* __restrict__ Cf, unsigned short* __restrict__ Cbf,
    int ldc, long long cGrp,
    int N, int kLen)
{
    __shared__ __align__(16) unsigned short As[2][128 * 64];
    __shared__ __align__(16) unsigned short Bs[2][128 * 64];

    int bx, by, z;
    xcd_remap(bx, by, z);

    const size_t aOff = (size_t)z * aGrpK;
    const size_t bOff = (size_t)z * bGrp;
    const size_t cOff = (size_t)z * cGrp;
    const int bias0 = z * biasGrp;

    const int t = threadIdx.x;
    const int rh = t >> 3;          // 0..31
    const int ch = t & 7;
    const int chs = ch ^ (rh & 7);
    const int rowBase = by * 128;
    const int colBase = bx * 128;

    const int wv = t >> 6, wm = wv >> 1, wn = wv & 1;
    const int l = t & 63, lr = l & 15, lk = l >> 4;
    const int xr = lr & 7;

    f32x4 acc[4][4] = {};
    const int nsteps = kLen >> 6;

    auto stage = [&](int buf, int kAbs) {
        const size_t kk = (size_t)(kAbs + chs * 8);
        #pragma unroll
        for (int it = 0; it < 4; ++it) {
            int ar = rowBase + rh + 32 * it;
            gload16(A + aOff + (size_t)ar * lda + kk, &As[buf][(rh + 32 * it) * 64 + ch * 8]);
            int bn = colBase + rh + 32 * it; bn = bn < N ? bn : N - 1;
            gload16(Bm + bOff + (size_t)bn * ldb + kk, &Bs[buf][(rh + 32 * it) * 64 + ch * 8]);
        }
    };

    stage(0, 0);

    for (int s = 0; s < nsteps; ++s) {
        const int cur = s & 1;
        __syncthreads();
        if (s + 1 < nsteps) stage(cur ^ 1, (s + 1) * 64);
        #pragma unroll
        for (int hh = 0; hh < 2; ++hh) {
            const int co = ((hh * 4 + lk) ^ xr) * 8;
            short8 af[4], bf[4];
            #pragma unroll
            for (int i = 0; i < 4; ++i)
                af[i] = *(const short8*)&As[cur][(wm * 64 + i * 16 + lr) * 64 + co];
            #pragma unroll
            for (int j = 0; j < 4; ++j)
                bf[j] = *(const short8*)&Bs[cur][(wn * 64 + j * 16 + lr) * 64 + co];
            #pragma unroll
            for (int i = 0; i < 4; ++i)
                #pragma unroll
                for (int j = 0; j < 4; ++j)
                    acc[i][j] = __builtin_amdgcn_mfma_f32_16x16x32_bf16(af[i], bf[j], acc[i][j], 0, 0, 0);
        }
    }

    #pragma unroll
    for (int i = 0; i < 4; ++i)
        #pragma unroll
        for (int j = 0; j < 4; ++j)
            #pragma unroll
            for (int r = 0; r < 4; ++r) {
                int row = rowBase + wm * 64 + i * 16 + lk * 4 + r;
                int col = colBase + wn * 64 + j * 16 + lr;
                if (col < N) {
                    float v = acc[i][j][r];
                    if (bias) v += bias[bias0 + col];
                    if (DO_TANH) v = tanhf(v);
                    size_t off = cOff + (size_t)row * ldc + col;
                    if (OUT_BF) Cbf[off] = f2bf(v);
                    else        Cf[off] = v;
                }
            }
}

// ---------------------------------------------------------------------------
// inputs split: [32768 rows][978] fp32 -> [32768][1024] bf16 hi/lo, zero-pad.
// 4 elems/thread via 2x float2 (978-float rows are 8B-aligned), ushort4 out.
// One block per row.
// ---------------------------------------------------------------------------
__global__ void split_rows_in(const float* __restrict__ src,
                              unsigned short* __restrict__ hi,
                              unsigned short* __restrict__ lo)
{
    int o = blockIdx.x;
    int c = threadIdx.x * 4;
    const float* s = src + (size_t)o * G_;
    float v[4];
    if (c + 3 < G_) {
        float2 a = *(const float2*)&s[c];
        float2 b = *(const float2*)&s[c + 2];
        v[0] = a.x; v[1] = a.y; v[2] = b.x; v[3] = b.y;
    } else {
        #pragma unroll
        for (int k = 0; k < 4; ++k) v[k] = (c + k < G_) ? s[c + k] : 0.f;
    }
    ushort4 h, lw;
    unsigned short* hp = (unsigned short*)&h;
    unsigned short* lp = (unsigned short*)&lw;
    #pragma unroll
    for (int k = 0; k < 4; ++k) {
        unsigned short hh = f2bf(v[k]);
        hp[k] = hh;
        lp[k] = f2bf(v[k] - bf2f(hh));
    }
    size_t d = (size_t)o * KP_ + c;
    *(ushort4*)&hi[d] = h;
    *(ushort4*)&lo[d] = lw;
}

// ---------------------------------------------------------------------------
// weight transpose + split (+K pad): src fp32 [g][Ksrc][N] -> bf16 [g][N][Kdst]
// lo == nullptr -> hi-only (plain bf16).
// ---------------------------------------------------------------------------
__global__ void transpose_split(const float* __restrict__ src, long long sGrp,
                                unsigned short* __restrict__ hi, unsigned short* __restrict__ lo,
                                long long dGrp, int Ksrc, int Kdst, int N)
{
    __shared__ float tile[32][33];
    int g = blockIdx.z;
    int k0 = blockIdx.y * 32, n0 = blockIdx.x * 32;
    int tx = threadIdx.x & 31, ty = threadIdx.x >> 5;
    #pragma unroll
    for (int i = 0; i < 4; ++i) {
        int k = k0 + ty + 8 * i, n = n0 + tx;
        float v = 0.f;
        if (k < Ksrc && n < N) v = src[(size_t)g * sGrp + (size_t)k * N + n];
        tile[ty + 8 * i][tx] = v;
    }
    __syncthreads();
    #pragma unroll
    for (int i = 0; i < 4; ++i) {
        int n = n0 + ty + 8 * i, k = k0 + tx;
        if (n < N && k < Kdst) {
            float v = tile[tx][ty + 8 * i];
            unsigned short h = f2bf(v);
            size_t off = (size_t)g * dGrp + (size_t)n * Kdst + k;
            hi[off] = h;
            if (lo) lo[off] = f2bf(v - bf2f(h));
        }
    }
}

// combine split-K partials of K2: z1 = tanh(sum_z P[z] + b1); 4 elems/thread
__global__ void combine4_tanh(const float* __restrict__ P, const float* __restrict__ b1,
                              float* __restrict__ z1)
{
    const int MN = B_ * D1_;
    int i = (blockIdx.x * 256 + threadIdx.x) * 4;
    float4 p0 = *(const float4*)&P[i];
    float4 p1 = *(const float4*)&P[i + MN];
    float4 p2 = *(const float4*)&P[i + 2 * MN];
    float4 p3 = *(const float4*)&P[i + 3 * MN];
    float4 bb = *(const float4*)&b1[i & (D1_ - 1)];
    float4 o;
    o.x = tanhf(p0.x + p1.x + p2.x + p3.x + bb.x);
    o.y = tanhf(p0.y + p1.y + p2.y + p3.y + bb.y);
    o.z = tanhf(p0.z + p1.z + p2.z + p3.z + bb.z);
    o.w = tanhf(p0.w + p1.w + p2.w + p3.w + bb.w);
    *(float4*)&z1[i] = o;
}

// ---------------------------------------------------------------------------
// fp32 vector GEMM for the tiny GEMMs K3/K5; optional bf16 out (Shi).
// ---------------------------------------------------------------------------
__global__ __launch_bounds__(256) void gemm_bt(
    const float* __restrict__ A, int aRow, int aGrp,
    const float* __restrict__ Bm, int bGrp,
    const float* __restrict__ bias, int biasGrp,
    float* __restrict__ C, int cRow, int cGrp,
    int M, int N, int K, int doTanh,
    unsigned short* __restrict__ Shi)
{
    __shared__ float As[16][68];
    __shared__ float Bs[16][64];

    const int g = blockIdx.z;
    const float* Ag = A  + (size_t)g * aGrp;
    const float* Bg = Bm + (size_t)g * bGrp;
    const float* bg = bias + (size_t)g * biasGrp;

    const int tid = threadIdx.x;
    const int tx = tid & 15, ty = tid >> 4;
    const int rowBase = blockIdx.y * 64;
    const int colBase = blockIdx.x * 64;

    float acc[4][4] = {};

    for (int k0 = 0; k0 < K; k0 += 16) {
        #pragma unroll
        for (int i = 0; i < 4; ++i) {
            int e = tid + 256 * i;
            int r = e >> 4, kk = e & 15;
            int kg = k0 + kk;
            float v = 0.f;
            if (kg < K) v = Ag[(size_t)(rowBase + r) * aRow + kg];
            As[kk][r] = v;
        }
        #pragma unroll
        for (int i = 0; i < 4; ++i) {
            int e = tid + 256 * i;
            int kk = e >> 6, c = e & 63;
            int kg = k0 + kk, cg = colBase + c;
            float v = 0.f;
            if (kg < K && cg < N) v = Bg[(size_t)kg * N + cg];
            Bs[kk][c] = v;
        }
        __syncthreads();
        #pragma unroll
        for (int kk = 0; kk < 16; ++kk) {
            float4 a4 = *(const float4*)&As[kk][ty * 4];
            float4 b4 = *(const float4*)&Bs[kk][tx * 4];
            float av[4] = {a4.x, a4.y, a4.z, a4.w};
            float bv[4] = {b4.x, b4.y, b4.z, b4.w};
            #pragma unroll
            for (int i = 0; i < 4; ++i)
                #pragma unroll
                for (int j = 0; j < 4; ++j)
                    acc[i][j] = fmaf(av[i], bv[j], acc[i][j]);
        }
        __syncthreads();
    }

    #pragma unroll
    for (int i = 0; i < 4; ++i) {
        int row = rowBase + ty * 4 + i;
        #pragma unroll
        for (int j = 0; j < 4; ++j) {
            int col = colBase + tx * 4 + j;
            if (col < N) {
                float v = acc[i][j] + bg[col];
                if (doTanh) v = tanhf(v);
                size_t off = (size_t)g * cGrp + (size_t)row * cRow + col;
                if (Shi) Shi[off] = f2bf(v);
                else     C[off] = v;
            }
        }
    }
}

// ---------------- VQ ----------------
__global__ void vq_prep(const float* __restrict__ cb, double* __restrict__ csq,
                        float* __restrict__ csqf, double* __restrict__ acc)
{
    int i = threadIdx.x;
    double s = 0.0;
    for (int d = 0; d < D2_; ++d) {
        double v = (double)cb[i * D2_ + d];
        s = fma(v, v, s);
    }
    csq[i] = s;
    csqf[i] = (float)s;
    if (i == 0) *acc = 0.0;
}

// f32 prescore (4 rows/block) + f64 re-score of margin candidates; semantics
// identical to all-f64 argmin with first-index tie-break.
__global__ __launch_bounds__(256) void vq_kernel(
    const float* __restrict__ z, const float* __restrict__ cb,
    const double* __restrict__ csq, const float* __restrict__ csqf,
    float* __restrict__ qst_out, float* __restrict__ q_ws,
    double* __restrict__ acc)
{
    __shared__ float  zsh[4][D2_];
    __shared__ float  rmin[256];
    __shared__ int    cand[64];
    __shared__ double dval[64];
    __shared__ int    ncand;
    __shared__ int    bestidx;
    __shared__ float  lsum[256];

    const int b0 = blockIdx.x * 4;
    const int t = threadIdx.x;

    ((float*)zsh)[t]       = z[(size_t)b0 * D2_ + t];
    ((float*)zsh)[t + 256] = z[(size_t)b0 * D2_ + t + 256];
    __syncthreads();

    float sc[2][4];
    #pragma unroll
    for (int ii = 0; ii < 2; ++ii) {
        int i = t + (ii << 8);
        const float4* cr = (const float4*)(cb + (size_t)i * D2_);
        float d0 = 0.f, d1 = 0.f, d2 = 0.f, d3 = 0.f;
        #pragma unroll 4
        for (int d4 = 0; d4 < 32; ++d4) {
            float4 c4 = cr[d4];
            float4 z0 = ((const float4*)zsh[0])[d4];
            float4 z1 = ((const float4*)zsh[1])[d4];
            float4 z2 = ((const float4*)zsh[2])[d4];
            float4 z3 = ((const float4*)zsh[3])[d4];
            d0 = fmaf(c4.x, z0.x, fmaf(c4.y, z0.y, fmaf(c4.z, z0.z, fmaf(c4.w, z0.w, d0))));
            d1 = fmaf(c4.x, z1.x, fmaf(c4.y, z1.y, fmaf(c4.z, z1.z, fmaf(c4.w, z1.w, d1))));
            d2 = fmaf(c4.x, z2.x, fmaf(c4.y, z2.y, fmaf(c4.z, z2.z, fmaf(c4.w, z2.w, d2))));
            d3 = fmaf(c4.x, z3.x, fmaf(c4.y, z3.y, fmaf(c4.z, z3.z, fmaf(c4.w, z3.w, d3))));
        }
        float cs = csqf[i];
        sc[ii][0] = cs - 2.f * d0;
        sc[ii][1] = cs - 2.f * d1;
        sc[ii][2] = cs - 2.f * d2;
        sc[ii][3] = cs - 2.f * d3;
    }

    float lossAcc = 0.f;
    for (int r = 0; r < 4; ++r) {
        rmin[t] = fminf(sc[0][r], sc[1][r]);
        __syncthreads();
        for (int off = 128; off > 0; off >>= 1) {
            if (t < off) rmin[t] = fminf(rmin[t], rmin[t + off]);
            __syncthreads();
        }
        float bestv = rmin[0];
        if (t == 0) ncand = 0;
        __syncthreads();
        #pragma unroll
        for (int ii = 0; ii < 2; ++ii)
            if (sc[ii][r] <= bestv + 1e-5f) {
                int p = atomicAdd(&ncand, 1);
                if (p < 64) cand[p] = t + (ii << 8);
            }
        __syncthreads();
        int nc = ncand < 64 ? ncand : 64;
        if (t < nc) {
            int i = cand[t];
            const float* cr = cb + (size_t)i * D2_;
            double dot = 0.0;
            for (int d = 0; d < D2_; ++d)
                dot = fma((double)cr[d], (double)zsh[r][d], dot);
            dval[t] = csq[i] - 2.0 * dot;
        }
        __syncthreads();
        if (t == 0) {
            double bv = 1e300; int bi = 0x7fffffff;
            for (int j2 = 0; j2 < nc; ++j2) {
                double v = dval[j2]; int i2 = cand[j2];
                if (v < bv || (v == bv && i2 < bi)) { bv = v; bi = i2; }
            }
            bestidx = bi;
        }
        __syncthreads();
        int idx = bestidx;
        if (t < D2_) {
            float qv = cb[(size_t)idx * D2_ + t];
            size_t o = (size_t)(b0 + r) * D2_ + t;
            qst_out[o] = qv;
            q_ws[o] = qv;
            float d = qv - zsh[r][t];
            lossAcc += d * d;
        }
        __syncthreads();
    }
    lsum[t] = lossAcc;
    __syncthreads();
    for (int off = 128; off > 0; off >>= 1) {
        if (t < off) lsum[t] += lsum[t + off];
        __syncthreads();
    }
    if (t == 0) atomicAdd(acc, (double)lsum[0]);
}

__global__ void finalize_loss(const double* __restrict__ acc, float* __restrict__ out0)
{
    out0[0] = (float)(1.25 * (*acc) / (double)((size_t)B_ * D2_));
}

// ---------------------------------------------------------------------------
extern "C" void kernel_launch(void* const* d_in, const int* in_sizes, int n_in,
                              void* d_out, int out_size, void* d_ws, size_t ws_size,
                              hipStream_t stream)
{
    const float* inputs = (const float*)d_in[0];
    const float* enc_w  = (const float*)d_in[1];
    const float* enc_b  = (const float*)d_in[2];
    const float* w1     = (const float*)d_in[3];
    const float* b1     = (const float*)d_in[4];
    const float* w2     = (const float*)d_in[5];
    const float* b2     = (const float*)d_in[6];
    const float* cb     = (const float*)d_in[7];
    const float* dw1    = (const float*)d_in[8];
    const float* db1    = (const float*)d_in[9];
    const float* dw2    = (const float*)d_in[10];
    const float* db2    = (const float*)d_in[11];
    const float* dec_w  = (const float*)d_in[12];
    const float* dec_b  = (const float*)d_in[13];

    float* out = (float*)d_out;
    float* x_recon = out + 1;
    float* qst     = out + 1 + (size_t)B_ * C_ * G_;

    const size_t MB = 1u << 20;
    const size_t NEED = 208 * MB;
    dim3 blk(256);

    if (ws_size >= NEED) {
        char* W = (char*)d_ws;
        unsigned short* ipad_hi = (unsigned short*)(W + 0);        // 64MB (dead after K1)
        unsigned short* ipad_lo = (unsigned short*)(W + 64 * MB);  // 64MB
        unsigned short* h_hi    = (unsigned short*)(W + 128 * MB); // 32MB
        unsigned short* h_lo    = (unsigned short*)(W + 160 * MB); // 32MB
        unsigned short* ewt_hi  = (unsigned short*)(W + 192 * MB); // 8MB
        unsigned short* ewt_lo  = (unsigned short*)(W + 200 * MB); // 8MB
        // region A reuse after K1:
        unsigned short* w1t_hi  = (unsigned short*)(W + 0);        // 2MB
        unsigned short* w1t_lo  = (unsigned short*)(W + 2 * MB);   // 2MB
        unsigned short* dw2t    = (unsigned short*)(W + 4 * MB);   // 2MB (bf16 only)
        unsigned short* dwt     = (unsigned short*)(W + 6 * MB);   // 7.65MB (bf16 only)
        float* partials = (float*)(W + 16 * MB);                   // 16MB
        float* z1 = (float*)(W + 32 * MB);                         // 4MB
        float* z  = (float*)(W + 36 * MB);                         // 2MB
        float* q  = (float*)(W + 38 * MB);                         // 2MB
        unsigned short* r1_bf = (unsigned short*)(W + 40 * MB);    // 2MB
        unsigned short* r_bf  = (unsigned short*)(W + 42 * MB);    // 32MB -> ends 74MB
        double* csq  = (double*)(W + 74 * MB);                     // 4KB
        double* acc  = (double*)(W + 74 * MB + 4096);
        float*  csqf = (float*)(W + 74 * MB + 4096 + 64);

        split_rows_in<<<dim3(B_ * C_), blk, 0, stream>>>(inputs, ipad_hi, ipad_lo);
        transpose_split<<<dim3(16, 32, 8), blk, 0, stream>>>(
            enc_w, (long long)G_ * D0_, ewt_hi, ewt_lo, (long long)D0_ * KP_, G_, KP_, D0_);

        // K1: h = tanh(inputs @ enc_w + enc_b), split-bf16 out
        mfma_split<1, 1><<<dim3(4, 32, 8), blk, 0, stream>>>(
            ipad_hi, ipad_lo, C_ * KP_, KP_,
            ewt_hi, ewt_lo, KP_, D0_ * KP_,
            enc_b, D0_,
            nullptr, h_hi, h_lo, CD_, 512LL,
            D0_, KP_, 0);

        transpose_split<<<dim3(8, 128, 1), blk, 0, stream>>>(
            w1, 0, w1t_hi, w1t_lo, 0, CD_, CD_, D1_);
        transpose_split<<<dim3(128, 8, 1), blk, 0, stream>>>(
            dw2, 0, dw2t, nullptr, 0, D1_, D1_, CD_);
        transpose_split<<<dim3(31, 16, 8), blk, 0, stream>>>(
            dec_w, (long long)D0_ * G_, dwt, nullptr, (long long)G_ * D0_, D0_, D0_, G_);

        // K2: partials[z] = h @ w1 (split-K = 4)
        mfma_split<0, 0><<<dim3(2, 32, 4), blk, 0, stream>>>(
            h_hi, h_lo, CD_, 0,
            w1t_hi, w1t_lo, CD_, 0,
            nullptr, 0,
            partials, nullptr, nullptr, D1_, (long long)B_ * D1_,
            D1_, CD_ / 4, 1);
        combine4_tanh<<<dim3(B_ * D1_ / 1024), blk, 0, stream>>>(partials, b1, z1);

        // K3: z = tanh(z1 @ w2 + b2)  (fp32)
        gemm_bt<<<dim3(2, 64, 1), blk, 0, stream>>>(
            z1, D1_, 0, w2, 0, b2, 0, z, D2_, 0, B_, D2_, D1_, 1, nullptr);

        // VQ
        vq_prep<<<dim3(1), dim3(K_), 0, stream>>>(cb, csq, csqf, acc);
        vq_kernel<<<dim3(B_ / 4), blk, 0, stream>>>(z, cb, csq, csqf, qst, q, acc);

        // K5: r1 = tanh(q @ dw1 + db1)  (fp32 compute, bf16 out)
        gemm_bt<<<dim3(4, 64, 1), blk, 0, stream>>>(
            q, D2_, 0, dw1, 0, db1, 0, nullptr, D1_, 0, B_, D1_, D2_, 1, r1_bf);

        // K6: r = tanh(r1 @ dw2 + db2), pure bf16
        mfma_bf<1, 1><<<dim3(32, 32, 1), blk, 0, stream>>>(
            r1_bf, D1_, 0,
            dw2t, D1_, 0,
            db2, 0,
            nullptr, r_bf, CD_, 0LL,
            CD_, D1_);

        // K7: x_recon = r @ dec_w + dec_b (grouped, pure bf16, fp32 out)
        mfma_bf<0, 0><<<dim3(8, 32, 8), blk, 0, stream>>>(
            r_bf, CD_, 512,
            dwt, D0_, (long long)G_ * D0_,
            dec_b, G_,
            x_recon, nullptr, C_ * G_, (long long)G_,
            G_, D0_);

        finalize_loss<<<dim3(1), dim3(1), 0, stream>>>(acc, out);
    } else {
        // -------- fallback: fp32 path --------
        float*  h   = (float*)d_ws;
        float*  z1  = h  + (size_t)B_ * CD_;
        float*  z   = z1 + (size_t)B_ * D1_;
        float*  q   = z  + (size_t)B_ * D2_;
        double* csq = (double*)(q + (size_t)B_ * D2_);
        double* acc = csq + K_;
        float*  csqf = (float*)(acc + 8);

        gemm_bt<<<dim3(D0_ / 64, B_ / 64, C_), blk, 0, stream>>>(
            inputs, C_ * G_, G_, enc_w, G_ * D0_, enc_b, D0_,
            h, CD_, D0_, B_, D0_, G_, 1, nullptr);
        gemm_bt<<<dim3(D1_ / 64, B_ / 64, 1), blk, 0, stream>>>(
            h, CD_, 0, w1, 0, b1, 0, z1, D1_, 0, B_, D1_, CD_, 1, nullptr);
        gemm_bt<<<dim3(D2_ / 64, B_ / 64, 1), blk, 0, stream>>>(
            z1, D1_, 0, w2, 0, b2, 0, z, D2_, 0, B_, D2_, D1_, 1, nullptr);
        vq_prep<<<dim3(1), dim3(K_), 0, stream>>>(cb, csq, csqf, acc);
        vq_kernel<<<dim3(B_ / 4), blk, 0, stream>>>(z, cb, csq, csqf, qst, q, acc);
        gemm_bt<<<dim3(D1_ / 64, B_ / 64, 1), blk, 0, stream>>>(
            q, D2_, 0, dw1, 0, db1, 0, z1, D1_, 0, B_, D1_, D2_, 1, nullptr);
        gemm_bt<<<dim3(CD_ / 64, B_ / 64, 1), blk, 0, stream>>>(
            z1, D1_, 0, dw2, 0, db2, 0, h, CD_, 0, B_, CD_, D1_, 1, nullptr);
        gemm_bt<<<dim3((G_ + 63) / 64, B_ / 64, C_), blk, 0, stream>>>(
            h, CD_, D0_, dec_w, D0_ * G_, dec_b, G_,
            x_recon, C_ * G_, G_, B_, G_, D0_, 0, nullptr);
        finalize_loss<<<dim3(1), dim3(1), 0, stream>>>(acc, out);
    }
}

// Round 6
// 485.412 us; speedup vs baseline: 4.5734x; 1.0521x over previous
//
#include <hip/hip_runtime.h>

#define B_   4096
#define C_   8
#define G_   978
#define D0_  512
#define D1_  256
#define D2_  128
#define K_   512
#define KP_  1024          // padded G (K of enc GEMM)
#define CD_  4096          // C_*D0_

typedef short short8 __attribute__((ext_vector_type(8)));
typedef float f32x4  __attribute__((ext_vector_type(4)));

// ---------------- bf16 helpers (RNE) ----------------
__device__ __forceinline__ unsigned short f2bf(float v) {
    union { float f; unsigned u; } x; x.f = v;
    unsigned r = (x.u + 0x7fffu + ((x.u >> 16) & 1u)) >> 16;
    return (unsigned short)r;
}
__device__ __forceinline__ float bf2f(unsigned short b) {
    union { unsigned u; float f; } x; x.u = ((unsigned)b) << 16;
    return x.f;
}

__device__ __forceinline__ void gload16(const unsigned short* g, unsigned short* l) {
    typedef const __attribute__((address_space(1))) unsigned int* gp_t;
    typedef __attribute__((address_space(3))) unsigned int* lp_t;
    __builtin_amdgcn_global_load_lds((gp_t)(const void*)g, (lp_t)(void*)l, 16, 0, 0);
}

// XCD-aware bijective remap (valid when nwg % 8 == 0)
__device__ __forceinline__ void xcd_remap(int& bx, int& by, int& z) {
    const int gx = gridDim.x, gy = gridDim.y;
    const int nwg = gx * gy * gridDim.z;
    int lin = blockIdx.x + gx * (blockIdx.y + gy * blockIdx.z);
    int logical = (nwg & 7) ? lin : ((lin & 7) * (nwg >> 3) + (lin >> 3));
    bx = logical % gx;
    by = (logical / gx) % gy;
    z  = logical / (gx * gy);
}

// ---------------------------------------------------------------------------
// Split-bf16 fused MFMA GEMM: C = [tanh]((Ahi+Alo)@(Bhi+Blo)^T + bias)
// Round-3 proven structure: tile 128x128, BK=64, 4 waves, single-buffered
// 64KB LDS, 2 barriers/K-step, chunk-XOR swizzle key (row&7) on both sides.
// A_F32: A is raw fp32 (lda/aGrp in floats); reg-stage + on-the-fly hi/lo
// split + ds_write to swizzled LDS (write pattern = uniform 8/bank, free);
// next step's A global loads issued before the compute barrier (T14-lite).
// Zero-pads k >= kValid.
// ---------------------------------------------------------------------------
template<int DO_TANH, int OUT_SPLIT, int A_F32>
__global__ __launch_bounds__(256, 2) void mfma_split(
    const unsigned short* __restrict__ Ahi, const unsigned short* __restrict__ Alo,
    const float* __restrict__ Af, int lda, int aGrp,
    const unsigned short* __restrict__ Bhi, const unsigned short* __restrict__ Blo,
    int ldb, int bGrp,
    const float* __restrict__ bias, int biasGrp,
    float* __restrict__ Cf, unsigned short* __restrict__ Chi, unsigned short* __restrict__ Clo,
    int ldc, long long cGrp,
    int N, int kLen, int kValid, int kSplit)
{
    __shared__ __align__(16) unsigned short AsH[128 * 64];
    __shared__ __align__(16) unsigned short AsL[128 * 64];
    __shared__ __align__(16) unsigned short BsH[128 * 64];
    __shared__ __align__(16) unsigned short BsL[128 * 64];

    int bx, by, z;
    xcd_remap(bx, by, z);

    const int g = kSplit ? 0 : z;
    const int kStart = kSplit ? z * kLen : 0;
    const size_t aOff = (size_t)g * aGrp;
    const size_t bOff = (size_t)g * bGrp;
    const size_t cOff = (size_t)z * cGrp;
    const int bias0 = g * biasGrp;

    const int t = threadIdx.x;
    const int rh = t >> 3;          // 0..31: row within 32-row staging stripe
    const int ch = t & 7;           // 16B chunk within 64-elem row
    const int chs = ch ^ (rh & 7);  // pre-swizzled source chunk (gload path)
    const int rowBase = by * 128;
    const int colBase = bx * 128;

    const int wv = t >> 6, wm = wv >> 1, wn = wv & 1;
    const int l = t & 63, lr = l & 15, lk = l >> 4;
    const int xr = lr & 7;          // read-side XOR key

    f32x4 acc[4][4] = {};
    float areg[4][8];               // A_F32 in-flight regs (static indexing only)

    auto loadA = [&](int k0) {
        const int kbase = kStart + k0 + ch * 8;
        #pragma unroll
        for (int it = 0; it < 4; ++it) {
            const float* src = Af + aOff + (size_t)(rowBase + rh + 32 * it) * lda + kbase;
            if (kbase + 7 < kValid) {
                float2 p0 = *(const float2*)&src[0];
                float2 p1 = *(const float2*)&src[2];
                float2 p2 = *(const float2*)&src[4];
                float2 p3 = *(const float2*)&src[6];
                areg[it][0] = p0.x; areg[it][1] = p0.y;
                areg[it][2] = p1.x; areg[it][3] = p1.y;
                areg[it][4] = p2.x; areg[it][5] = p2.y;
                areg[it][6] = p3.x; areg[it][7] = p3.y;
            } else {
                #pragma unroll
                for (int j = 0; j < 8; ++j)
                    areg[it][j] = (kbase + j < kValid) ? src[j] : 0.f;
            }
        }
    };

    auto writeA = [&]() {
        #pragma unroll
        for (int it = 0; it < 4; ++it) {
            int row = rh + 32 * it;
            short8 h8, l8;
            #pragma unroll
            for (int j = 0; j < 8; ++j) {
                unsigned short hh = f2bf(areg[it][j]);
                ((unsigned short*)&h8)[j] = hh;
                ((unsigned short*)&l8)[j] = f2bf(areg[it][j] - bf2f(hh));
            }
            int woff = row * 64 + (ch ^ (row & 7)) * 8;
            *(short8*)&AsH[woff] = h8;
            *(short8*)&AsL[woff] = l8;
        }
    };

    auto stageA_lds = [&](int k0) {
        const size_t kk = (size_t)(kStart + k0 + chs * 8);
        #pragma unroll
        for (int it = 0; it < 4; ++it) {
            size_t ao = aOff + (size_t)(rowBase + rh + 32 * it) * lda + kk;
            int dst = (rh + 32 * it) * 64 + ch * 8;
            gload16(Ahi + ao, &AsH[dst]);
            gload16(Alo + ao, &AsL[dst]);
        }
    };

    auto stageB = [&](int k0) {
        const size_t kk = (size_t)(kStart + k0 + chs * 8);
        #pragma unroll
        for (int it = 0; it < 4; ++it) {
            int bn = colBase + rh + 32 * it; bn = bn < N ? bn : N - 1;
            size_t bo = bOff + (size_t)bn * ldb + kk;
            int dst = (rh + 32 * it) * 64 + ch * 8;
            gload16(Bhi + bo, &BsH[dst]);
            gload16(Blo + bo, &BsL[dst]);
        }
    };

    if (A_F32) loadA(0);

    for (int k0 = 0; k0 < kLen; k0 += 64) {
        if (A_F32) {
            writeA();                       // LDS free: prev compute barrier passed
            stageB(k0);
            if (k0 + 64 < kLen) loadA(k0 + 64);   // overlap next A fetch w/ compute
        } else {
            stageA_lds(k0);
            stageB(k0);
        }
        __syncthreads();
        #pragma unroll
        for (int s = 0; s < 2; ++s) {
            const int c = s * 4 + lk;
            const int co = (c ^ xr) * 8;
            short8 aH[4], aL[4], bH[4], bL[4];
            #pragma unroll
            for (int i = 0; i < 4; ++i) {
                int off = (wm * 64 + i * 16 + lr) * 64 + co;
                aH[i] = *(const short8*)&AsH[off];
                aL[i] = *(const short8*)&AsL[off];
            }
            #pragma unroll
            for (int j = 0; j < 4; ++j) {
                int off = (wn * 64 + j * 16 + lr) * 64 + co;
                bH[j] = *(const short8*)&BsH[off];
                bL[j] = *(const short8*)&BsL[off];
            }
            #pragma unroll
            for (int i = 0; i < 4; ++i)
                #pragma unroll
                for (int j = 0; j < 4; ++j) {
                    acc[i][j] = __builtin_amdgcn_mfma_f32_16x16x32_bf16(aH[i], bH[j], acc[i][j], 0, 0, 0);
                    acc[i][j] = __builtin_amdgcn_mfma_f32_16x16x32_bf16(aH[i], bL[j], acc[i][j], 0, 0, 0);
                    acc[i][j] = __builtin_amdgcn_mfma_f32_16x16x32_bf16(aL[i], bH[j], acc[i][j], 0, 0, 0);
                }
        }
        __syncthreads();
    }

    #pragma unroll
    for (int i = 0; i < 4; ++i)
        #pragma unroll
        for (int j = 0; j < 4; ++j)
            #pragma unroll
            for (int r = 0; r < 4; ++r) {
                int row = rowBase + wm * 64 + i * 16 + lk * 4 + r;
                int col = colBase + wn * 64 + j * 16 + lr;
                if (col < N) {
                    float v = acc[i][j][r];
                    if (bias) v += bias[bias0 + col];
                    if (DO_TANH) v = tanhf(v);
                    size_t off = cOff + (size_t)row * ldc + col;
                    if (OUT_SPLIT) {
                        unsigned short hh = f2bf(v);
                        Chi[off] = hh;
                        Clo[off] = f2bf(v - bf2f(hh));
                    } else {
                        Cf[off] = v;
                    }
                }
            }
}

// ---------------------------------------------------------------------------
// Pure-bf16 MFMA GEMM (decoder path): C = [tanh](A @ B^T + bias)
// Tile 128x128, BK=64, double-buffered (2x2x16KB = 64KB), prefetch overlap,
// (row&7) chunk-XOR swizzle.
// ---------------------------------------------------------------------------
template<int DO_TANH, int OUT_BF>
__global__ __launch_bounds__(256, 2) void mfma_bf(
    const unsigned short* __restrict__ A, int lda, int aGrpK,
    const unsigned short* __restrict__ Bm, int ldb, long long bGrp,
    const float* __restrict__ bias, int biasGrp,
    float* __restrict__ Cf, unsigned short* __restrict__ Cbf,
    int ldc, long long cGrp,
    int N, int kLen)
{
    __shared__ __align__(16) unsigned short As[2][128 * 64];
    __shared__ __align__(16) unsigned short Bs[2][128 * 64];

    int bx, by, z;
    xcd_remap(bx, by, z);

    const size_t aOff = (size_t)z * aGrpK;
    const size_t bOff = (size_t)z * bGrp;
    const size_t cOff = (size_t)z * cGrp;
    const int bias0 = z * biasGrp;

    const int t = threadIdx.x;
    const int rh = t >> 3;          // 0..31
    const int ch = t & 7;
    const int chs = ch ^ (rh & 7);
    const int rowBase = by * 128;
    const int colBase = bx * 128;

    const int wv = t >> 6, wm = wv >> 1, wn = wv & 1;
    const int l = t & 63, lr = l & 15, lk = l >> 4;
    const int xr = lr & 7;

    f32x4 acc[4][4] = {};
    const int nsteps = kLen >> 6;

    auto stage = [&](int buf, int kAbs) {
        const size_t kk = (size_t)(kAbs + chs * 8);
        #pragma unroll
        for (int it = 0; it < 4; ++it) {
            int ar = rowBase + rh + 32 * it;
            gload16(A + aOff + (size_t)ar * lda + kk, &As[buf][(rh + 32 * it) * 64 + ch * 8]);
            int bn = colBase + rh + 32 * it; bn = bn < N ? bn : N - 1;
            gload16(Bm + bOff + (size_t)bn * ldb + kk, &Bs[buf][(rh + 32 * it) * 64 + ch * 8]);
        }
    };

    stage(0, 0);

    for (int s = 0; s < nsteps; ++s) {
        const int cur = s & 1;
        __syncthreads();
        if (s + 1 < nsteps) stage(cur ^ 1, (s + 1) * 64);
        #pragma unroll
        for (int hh = 0; hh < 2; ++hh) {
            const int co = ((hh * 4 + lk) ^ xr) * 8;
            short8 af[4], bf[4];
            #pragma unroll
            for (int i = 0; i < 4; ++i)
                af[i] = *(const short8*)&As[cur][(wm * 64 + i * 16 + lr) * 64 + co];
            #pragma unroll
            for (int j = 0; j < 4; ++j)
                bf[j] = *(const short8*)&Bs[cur][(wn * 64 + j * 16 + lr) * 64 + co];
            #pragma unroll
            for (int i = 0; i < 4; ++i)
                #pragma unroll
                for (int j = 0; j < 4; ++j)
                    acc[i][j] = __builtin_amdgcn_mfma_f32_16x16x32_bf16(af[i], bf[j], acc[i][j], 0, 0, 0);
        }
    }

    #pragma unroll
    for (int i = 0; i < 4; ++i)
        #pragma unroll
        for (int j = 0; j < 4; ++j)
            #pragma unroll
            for (int r = 0; r < 4; ++r) {
                int row = rowBase + wm * 64 + i * 16 + lk * 4 + r;
                int col = colBase + wn * 64 + j * 16 + lr;
                if (col < N) {
                    float v = acc[i][j][r];
                    if (bias) v += bias[bias0 + col];
                    if (DO_TANH) v = tanhf(v);
                    size_t off = cOff + (size_t)row * ldc + col;
                    if (OUT_BF) Cbf[off] = f2bf(v);
                    else        Cf[off] = v;
                }
            }
}

// ---------------------------------------------------------------------------
// weight transpose + split (+K pad): src fp32 [g][Ksrc][N] -> bf16 [g][N][Kdst]
// lo == nullptr -> hi-only (plain bf16).
// ---------------------------------------------------------------------------
__global__ void transpose_split(const float* __restrict__ src, long long sGrp,
                                unsigned short* __restrict__ hi, unsigned short* __restrict__ lo,
                                long long dGrp, int Ksrc, int Kdst, int N)
{
    __shared__ float tile[32][33];
    int g = blockIdx.z;
    int k0 = blockIdx.y * 32, n0 = blockIdx.x * 32;
    int tx = threadIdx.x & 31, ty = threadIdx.x >> 5;
    #pragma unroll
    for (int i = 0; i < 4; ++i) {
        int k = k0 + ty + 8 * i, n = n0 + tx;
        float v = 0.f;
        if (k < Ksrc && n < N) v = src[(size_t)g * sGrp + (size_t)k * N + n];
        tile[ty + 8 * i][tx] = v;
    }
    __syncthreads();
    #pragma unroll
    for (int i = 0; i < 4; ++i) {
        int n = n0 + ty + 8 * i, k = k0 + tx;
        if (n < N && k < Kdst) {
            float v = tile[tx][ty + 8 * i];
            unsigned short h = f2bf(v);
            size_t off = (size_t)g * dGrp + (size_t)n * Kdst + k;
            hi[off] = h;
            if (lo) lo[off] = f2bf(v - bf2f(h));
        }
    }
}

// combine split-K partials of K2: z1 = tanh(sum_z P[z] + b1); 4 elems/thread
__global__ void combine4_tanh(const float* __restrict__ P, const float* __restrict__ b1,
                              float* __restrict__ z1)
{
    const int MN = B_ * D1_;
    int i = (blockIdx.x * 256 + threadIdx.x) * 4;
    float4 p0 = *(const float4*)&P[i];
    float4 p1 = *(const float4*)&P[i + MN];
    float4 p2 = *(const float4*)&P[i + 2 * MN];
    float4 p3 = *(const float4*)&P[i + 3 * MN];
    float4 bb = *(const float4*)&b1[i & (D1_ - 1)];
    float4 o;
    o.x = tanhf(p0.x + p1.x + p2.x + p3.x + bb.x);
    o.y = tanhf(p0.y + p1.y + p2.y + p3.y + bb.y);
    o.z = tanhf(p0.z + p1.z + p2.z + p3.z + bb.z);
    o.w = tanhf(p0.w + p1.w + p2.w + p3.w + bb.w);
    *(float4*)&z1[i] = o;
}

// ---------------------------------------------------------------------------
// fp32 vector GEMM for the tiny GEMMs K3/K5; optional bf16 out (Shi).
// ---------------------------------------------------------------------------
__global__ __launch_bounds__(256) void gemm_bt(
    const float* __restrict__ A, int aRow, int aGrp,
    const float* __restrict__ Bm, int bGrp,
    const float* __restrict__ bias, int biasGrp,
    float* __restrict__ C, int cRow, int cGrp,
    int M, int N, int K, int doTanh,
    unsigned short* __restrict__ Shi)
{
    __shared__ float As[16][68];
    __shared__ float Bs[16][64];

    const int g = blockIdx.z;
    const float* Ag = A  + (size_t)g * aGrp;
    const float* Bg = Bm + (size_t)g * bGrp;
    const float* bg = bias + (size_t)g * biasGrp;

    const int tid = threadIdx.x;
    const int tx = tid & 15, ty = tid >> 4;
    const int rowBase = blockIdx.y * 64;
    const int colBase = blockIdx.x * 64;

    float acc[4][4] = {};

    for (int k0 = 0; k0 < K; k0 += 16) {
        #pragma unroll
        for (int i = 0; i < 4; ++i) {
            int e = tid + 256 * i;
            int r = e >> 4, kk = e & 15;
            int kg = k0 + kk;
            float v = 0.f;
            if (kg < K) v = Ag[(size_t)(rowBase + r) * aRow + kg];
            As[kk][r] = v;
        }
        #pragma unroll
        for (int i = 0; i < 4; ++i) {
            int e = tid + 256 * i;
            int kk = e >> 6, c = e & 63;
            int kg = k0 + kk, cg = colBase + c;
            float v = 0.f;
            if (kg < K && cg < N) v = Bg[(size_t)kg * N + cg];
            Bs[kk][c] = v;
        }
        __syncthreads();
        #pragma unroll
        for (int kk = 0; kk < 16; ++kk) {
            float4 a4 = *(const float4*)&As[kk][ty * 4];
            float4 b4 = *(const float4*)&Bs[kk][tx * 4];
            float av[4] = {a4.x, a4.y, a4.z, a4.w};
            float bv[4] = {b4.x, b4.y, b4.z, b4.w};
            #pragma unroll
            for (int i = 0; i < 4; ++i)
                #pragma unroll
                for (int j = 0; j < 4; ++j)
                    acc[i][j] = fmaf(av[i], bv[j], acc[i][j]);
        }
        __syncthreads();
    }

    #pragma unroll
    for (int i = 0; i < 4; ++i) {
        int row = rowBase + ty * 4 + i;
        #pragma unroll
        for (int j = 0; j < 4; ++j) {
            int col = colBase + tx * 4 + j;
            if (col < N) {
                float v = acc[i][j] + bg[col];
                if (doTanh) v = tanhf(v);
                size_t off = (size_t)g * cGrp + (size_t)row * cRow + col;
                if (Shi) Shi[off] = f2bf(v);
                else     C[off] = v;
            }
        }
    }
}

// ---------------- VQ ----------------
__global__ void vq_prep(const float* __restrict__ cb, double* __restrict__ csq,
                        float* __restrict__ csqf, double* __restrict__ acc)
{
    int i = threadIdx.x;
    double s = 0.0;
    for (int d = 0; d < D2_; ++d) {
        double v = (double)cb[i * D2_ + d];
        s = fma(v, v, s);
    }
    csq[i] = s;
    csqf[i] = (float)s;
    if (i == 0) *acc = 0.0;
}

// f32 prescore (4 rows/block) + f64 re-score of margin candidates; semantics
// identical to all-f64 argmin with first-index tie-break.
__global__ __launch_bounds__(256) void vq_kernel(
    const float* __restrict__ z, const float* __restrict__ cb,
    const double* __restrict__ csq, const float* __restrict__ csqf,
    float* __restrict__ qst_out, float* __restrict__ q_ws,
    double* __restrict__ acc)
{
    __shared__ float  zsh[4][D2_];
    __shared__ float  rmin[256];
    __shared__ int    cand[64];
    __shared__ double dval[64];
    __shared__ int    ncand;
    __shared__ int    bestidx;
    __shared__ float  lsum[256];

    const int b0 = blockIdx.x * 4;
    const int t = threadIdx.x;

    ((float*)zsh)[t]       = z[(size_t)b0 * D2_ + t];
    ((float*)zsh)[t + 256] = z[(size_t)b0 * D2_ + t + 256];
    __syncthreads();

    float sc[2][4];
    #pragma unroll
    for (int ii = 0; ii < 2; ++ii) {
        int i = t + (ii << 8);
        const float4* cr = (const float4*)(cb + (size_t)i * D2_);
        float d0 = 0.f, d1 = 0.f, d2 = 0.f, d3 = 0.f;
        #pragma unroll 4
        for (int d4 = 0; d4 < 32; ++d4) {
            float4 c4 = cr[d4];
            float4 z0 = ((const float4*)zsh[0])[d4];
            float4 z1 = ((const float4*)zsh[1])[d4];
            float4 z2 = ((const float4*)zsh[2])[d4];
            float4 z3 = ((const float4*)zsh[3])[d4];
            d0 = fmaf(c4.x, z0.x, fmaf(c4.y, z0.y, fmaf(c4.z, z0.z, fmaf(c4.w, z0.w, d0))));
            d1 = fmaf(c4.x, z1.x, fmaf(c4.y, z1.y, fmaf(c4.z, z1.z, fmaf(c4.w, z1.w, d1))));
            d2 = fmaf(c4.x, z2.x, fmaf(c4.y, z2.y, fmaf(c4.z, z2.z, fmaf(c4.w, z2.w, d2))));
            d3 = fmaf(c4.x, z3.x, fmaf(c4.y, z3.y, fmaf(c4.z, z3.z, fmaf(c4.w, z3.w, d3))));
        }
        float cs = csqf[i];
        sc[ii][0] = cs - 2.f * d0;
        sc[ii][1] = cs - 2.f * d1;
        sc[ii][2] = cs - 2.f * d2;
        sc[ii][3] = cs - 2.f * d3;
    }

    float lossAcc = 0.f;
    for (int r = 0; r < 4; ++r) {
        rmin[t] = fminf(sc[0][r], sc[1][r]);
        __syncthreads();
        for (int off = 128; off > 0; off >>= 1) {
            if (t < off) rmin[t] = fminf(rmin[t], rmin[t + off]);
            __syncthreads();
        }
        float bestv = rmin[0];
        if (t == 0) ncand = 0;
        __syncthreads();
        #pragma unroll
        for (int ii = 0; ii < 2; ++ii)
            if (sc[ii][r] <= bestv + 1e-5f) {
                int p = atomicAdd(&ncand, 1);
                if (p < 64) cand[p] = t + (ii << 8);
            }
        __syncthreads();
        int nc = ncand < 64 ? ncand : 64;
        if (t < nc) {
            int i = cand[t];
            const float* cr = cb + (size_t)i * D2_;
            double dot = 0.0;
            for (int d = 0; d < D2_; ++d)
                dot = fma((double)cr[d], (double)zsh[r][d], dot);
            dval[t] = csq[i] - 2.0 * dot;
        }
        __syncthreads();
        if (t == 0) {
            double bv = 1e300; int bi = 0x7fffffff;
            for (int j2 = 0; j2 < nc; ++j2) {
                double v = dval[j2]; int i2 = cand[j2];
                if (v < bv || (v == bv && i2 < bi)) { bv = v; bi = i2; }
            }
            bestidx = bi;
        }
        __syncthreads();
        int idx = bestidx;
        if (t < D2_) {
            float qv = cb[(size_t)idx * D2_ + t];
            size_t o = (size_t)(b0 + r) * D2_ + t;
            qst_out[o] = qv;
            q_ws[o] = qv;
            float d = qv - zsh[r][t];
            lossAcc += d * d;
        }
        __syncthreads();
    }
    lsum[t] = lossAcc;
    __syncthreads();
    for (int off = 128; off > 0; off >>= 1) {
        if (t < off) lsum[t] += lsum[t + off];
        __syncthreads();
    }
    if (t == 0) atomicAdd(acc, (double)lsum[0]);
}

__global__ void finalize_loss(const double* __restrict__ acc, float* __restrict__ out0)
{
    out0[0] = (float)(1.25 * (*acc) / (double)((size_t)B_ * D2_));
}

// ---------------------------------------------------------------------------
extern "C" void kernel_launch(void* const* d_in, const int* in_sizes, int n_in,
                              void* d_out, int out_size, void* d_ws, size_t ws_size,
                              hipStream_t stream)
{
    const float* inputs = (const float*)d_in[0];
    const float* enc_w  = (const float*)d_in[1];
    const float* enc_b  = (const float*)d_in[2];
    const float* w1     = (const float*)d_in[3];
    const float* b1     = (const float*)d_in[4];
    const float* w2     = (const float*)d_in[5];
    const float* b2     = (const float*)d_in[6];
    const float* cb     = (const float*)d_in[7];
    const float* dw1    = (const float*)d_in[8];
    const float* db1    = (const float*)d_in[9];
    const float* dw2    = (const float*)d_in[10];
    const float* db2    = (const float*)d_in[11];
    const float* dec_w  = (const float*)d_in[12];
    const float* dec_b  = (const float*)d_in[13];

    float* out = (float*)d_out;
    float* x_recon = out + 1;
    float* qst     = out + 1 + (size_t)B_ * C_ * G_;

    const size_t MB = 1u << 20;
    const size_t NEED = 156 * MB;
    dim3 blk(256);

    if (ws_size >= NEED) {
        char* W = (char*)d_ws;
        unsigned short* ewt_hi = (unsigned short*)(W + 0);         // 8MB
        unsigned short* ewt_lo = (unsigned short*)(W + 8 * MB);    // 8MB
        unsigned short* h_hi   = (unsigned short*)(W + 16 * MB);   // 32MB
        unsigned short* h_lo   = (unsigned short*)(W + 48 * MB);   // 32MB
        unsigned short* w1t_hi = (unsigned short*)(W + 80 * MB);   // 2MB
        unsigned short* w1t_lo = (unsigned short*)(W + 82 * MB);   // 2MB
        unsigned short* dw2t   = (unsigned short*)(W + 84 * MB);   // 2MB (bf16 only)
        unsigned short* dwt    = (unsigned short*)(W + 86 * MB);   // 7.65MB (bf16 only)
        float* partials = (float*)(W + 94 * MB);                   // 16MB
        float* z1 = (float*)(W + 110 * MB);                        // 4MB
        float* z  = (float*)(W + 114 * MB);                        // 2MB
        float* q  = (float*)(W + 116 * MB);                        // 2MB
        unsigned short* r1_bf = (unsigned short*)(W + 118 * MB);   // 2MB
        unsigned short* r_bf  = (unsigned short*)(W + 120 * MB);   // 32MB -> ends 152MB
        double* csq  = (double*)(W + 152 * MB);                    // 4KB
        double* acc  = (double*)(W + 152 * MB + 4096);
        float*  csqf = (float*)(W + 152 * MB + 4096 + 64);

        // weight prep (all before K1; inputs are split on the fly in K1)
        transpose_split<<<dim3(16, 32, 8), blk, 0, stream>>>(
            enc_w, (long long)G_ * D0_, ewt_hi, ewt_lo, (long long)D0_ * KP_, G_, KP_, D0_);
        transpose_split<<<dim3(8, 128, 1), blk, 0, stream>>>(
            w1, 0, w1t_hi, w1t_lo, 0, CD_, CD_, D1_);
        transpose_split<<<dim3(128, 8, 1), blk, 0, stream>>>(
            dw2, 0, dw2t, nullptr, 0, D1_, D1_, CD_);
        transpose_split<<<dim3(31, 16, 8), blk, 0, stream>>>(
            dec_w, (long long)D0_ * G_, dwt, nullptr, (long long)G_ * D0_, D0_, D0_, G_);

        // K1: h = tanh(inputs @ enc_w + enc_b); A = raw fp32, split on the fly
        mfma_split<1, 1, 1><<<dim3(4, 32, 8), blk, 0, stream>>>(
            nullptr, nullptr, inputs, C_ * G_, G_,
            ewt_hi, ewt_lo, KP_, D0_ * KP_,
            enc_b, D0_,
            nullptr, h_hi, h_lo, CD_, 512LL,
            D0_, KP_, G_, 0);

        // K2: partials[z] = h @ w1 (split-K = 4)
        mfma_split<0, 0, 0><<<dim3(2, 32, 4), blk, 0, stream>>>(
            h_hi, h_lo, nullptr, CD_, 0,
            w1t_hi, w1t_lo, CD_, 0,
            nullptr, 0,
            partials, nullptr, nullptr, D1_, (long long)B_ * D1_,
            D1_, CD_ / 4, CD_ / 4, 1);
        combine4_tanh<<<dim3(B_ * D1_ / 1024), blk, 0, stream>>>(partials, b1, z1);

        // K3: z = tanh(z1 @ w2 + b2)  (fp32)
        gemm_bt<<<dim3(2, 64, 1), blk, 0, stream>>>(
            z1, D1_, 0, w2, 0, b2, 0, z, D2_, 0, B_, D2_, D1_, 1, nullptr);

        // VQ
        vq_prep<<<dim3(1), dim3(K_), 0, stream>>>(cb, csq, csqf, acc);
        vq_kernel<<<dim3(B_ / 4), blk, 0, stream>>>(z, cb, csq, csqf, qst, q, acc);

        // K5: r1 = tanh(q @ dw1 + db1)  (fp32 compute, bf16 out)
        gemm_bt<<<dim3(4, 64, 1), blk, 0, stream>>>(
            q, D2_, 0, dw1, 0, db1, 0, nullptr, D1_, 0, B_, D1_, D2_, 1, r1_bf);

        // K6: r = tanh(r1 @ dw2 + db2), pure bf16
        mfma_bf<1, 1><<<dim3(32, 32, 1), blk, 0, stream>>>(
            r1_bf, D1_, 0,
            dw2t, D1_, 0,
            db2, 0,
            nullptr, r_bf, CD_, 0LL,
            CD_, D1_);

        // K7: x_recon = r @ dec_w + dec_b (grouped, pure bf16, fp32 out)
        mfma_bf<0, 0><<<dim3(8, 32, 8), blk, 0, stream>>>(
            r_bf, CD_, 512,
            dwt, D0_, (long long)G_ * D0_,
            dec_b, G_,
            x_recon, nullptr, C_ * G_, (long long)G_,
            G_, D0_);

        finalize_loss<<<dim3(1), dim3(1), 0, stream>>>(acc, out);
    } else {
        // -------- fallback: fp32 path --------
        float*  h   = (float*)d_ws;
        float*  z1  = h  + (size_t)B_ * CD_;
        float*  z   = z1 + (size_t)B_ * D1_;
        float*  q   = z  + (size_t)B_ * D2_;
        double* csq = (double*)(q + (size_t)B_ * D2_);
        double* acc = csq + K_;
        float*  csqf = (float*)(acc + 8);

        gemm_bt<<<dim3(D0_ / 64, B_ / 64, C_), blk, 0, stream>>>(
            inputs, C_ * G_, G_, enc_w, G_ * D0_, enc_b, D0_,
            h, CD_, D0_, B_, D0_, G_, 1, nullptr);
        gemm_bt<<<dim3(D1_ / 64, B_ / 64, 1), blk, 0, stream>>>(
            h, CD_, 0, w1, 0, b1, 0, z1, D1_, 0, B_, D1_, CD_, 1, nullptr);
        gemm_bt<<<dim3(D2_ / 64, B_ / 64, 1), blk, 0, stream>>>(
            z1, D1_, 0, w2, 0, b2, 0, z, D2_, 0, B_, D2_, D1_, 1, nullptr);
        vq_prep<<<dim3(1), dim3(K_), 0, stream>>>(cb, csq, csqf, acc);
        vq_kernel<<<dim3(B_ / 4), blk, 0, stream>>>(z, cb, csq, csqf, qst, q, acc);
        gemm_bt<<<dim3(D1_ / 64, B_ / 64, 1), blk, 0, stream>>>(
            q, D2_, 0, dw1, 0, db1, 0, z1, D1_, 0, B_, D1_, D2_, 1, nullptr);
        gemm_bt<<<dim3(CD_ / 64, B_ / 64, 1), blk, 0, stream>>>(
            z1, D1_, 0, dw2, 0, db2, 0, h, CD_, 0, B_, CD_, D1_, 1, nullptr);
        gemm_bt<<<dim3((G_ + 63) / 64, B_ / 64, C_), blk, 0, stream>>>(
            h, CD_, D0_, dec_w, D0_ * G_, dec_b, G_,
            x_recon, C_ * G_, G_, B_, G_, D0_, 0, nullptr);
        finalize_loss<<<dim3(1), dim3(1), 0, stream>>>(acc, out);
    }
}

// Round 7
// 468.089 us; speedup vs baseline: 4.7426x; 1.0370x over previous
//
#include <hip/hip_runtime.h>

#define B_   4096
#define C_   8
#define G_   978
#define D0_  512
#define D1_  256
#define D2_  128
#define K_   512
#define KP_  1024          // padded G (K of enc GEMM)
#define CD_  4096          // C_*D0_

typedef short short8 __attribute__((ext_vector_type(8)));
typedef float f32x4  __attribute__((ext_vector_type(4)));

// ---------------- bf16 helpers (RNE) ----------------
__device__ __forceinline__ unsigned short f2bf(float v) {
    union { float f; unsigned u; } x; x.f = v;
    unsigned r = (x.u + 0x7fffu + ((x.u >> 16) & 1u)) >> 16;
    return (unsigned short)r;
}
__device__ __forceinline__ float bf2f(unsigned short b) {
    union { unsigned u; float f; } x; x.u = ((unsigned)b) << 16;
    return x.f;
}
// packed RNE f32x2 -> bf16x2 (lo16 = a, hi16 = b); HW RNE == f2bf bitwise
__device__ __forceinline__ unsigned cvtpk(float a, float b) {
    unsigned r;
    asm("v_cvt_pk_bf16_f32 %0, %1, %2" : "=v"(r) : "v"(a), "v"(b));
    return r;
}
__device__ __forceinline__ float ubits(unsigned u) {
    union { unsigned u; float f; } x; x.u = u;
    return x.f;
}
__device__ __forceinline__ unsigned fbits(float f) {
    union { float f; unsigned u; } x; x.f = f;
    return x.u;
}

__device__ __forceinline__ void gload16(const unsigned short* g, unsigned short* l) {
    typedef const __attribute__((address_space(1))) unsigned int* gp_t;
    typedef __attribute__((address_space(3))) unsigned int* lp_t;
    __builtin_amdgcn_global_load_lds((gp_t)(const void*)g, (lp_t)(void*)l, 16, 0, 0);
}

// XCD-aware bijective remap (valid when nwg % 8 == 0)
__device__ __forceinline__ void xcd_remap(int& bx, int& by, int& z) {
    const int gx = gridDim.x, gy = gridDim.y;
    const int nwg = gx * gy * gridDim.z;
    int lin = blockIdx.x + gx * (blockIdx.y + gy * blockIdx.z);
    int logical = (nwg & 7) ? lin : ((lin & 7) * (nwg >> 3) + (lin >> 3));
    bx = logical % gx;
    by = (logical / gx) % gy;
    z  = logical / (gx * gy);
}

// ---------------------------------------------------------------------------
// Split-bf16 fused MFMA GEMM: C = [tanh]((Ahi+Alo)@(Bhi+Blo)^T + bias)
// Tile 128x128, BK=64, 4 waves, single-buffered 64KB LDS, 2 barriers/K-step,
// chunk-XOR swizzle key (row&7) on both sides.
// A_F32: A is raw fp32; reg-stage + cvt_pk hi/lo split + swizzled ds_write.
// Next A-tile's global loads are issued AFTER barrier1 (inside the compute
// region) so HBM latency hides under the 96-MFMA phase; barrier2 (needed by
// writeA anyway) drains them.
// ---------------------------------------------------------------------------
template<int DO_TANH, int OUT_SPLIT, int A_F32>
__global__ __launch_bounds__(256, 2) void mfma_split(
    const unsigned short* __restrict__ Ahi, const unsigned short* __restrict__ Alo,
    const float* __restrict__ Af, int lda, int aGrp,
    const unsigned short* __restrict__ Bhi, const unsigned short* __restrict__ Blo,
    int ldb, int bGrp,
    const float* __restrict__ bias, int biasGrp,
    float* __restrict__ Cf, unsigned short* __restrict__ Chi, unsigned short* __restrict__ Clo,
    int ldc, long long cGrp,
    int N, int kLen, int kValid, int kSplit)
{
    __shared__ __align__(16) unsigned short AsH[128 * 64];
    __shared__ __align__(16) unsigned short AsL[128 * 64];
    __shared__ __align__(16) unsigned short BsH[128 * 64];
    __shared__ __align__(16) unsigned short BsL[128 * 64];

    int bx, by, z;
    xcd_remap(bx, by, z);

    const int g = kSplit ? 0 : z;
    const int kStart = kSplit ? z * kLen : 0;
    const size_t aOff = (size_t)g * aGrp;
    const size_t bOff = (size_t)g * bGrp;
    const size_t cOff = (size_t)z * cGrp;
    const int bias0 = g * biasGrp;

    const int t = threadIdx.x;
    const int rh = t >> 3;          // 0..31: row within 32-row staging stripe
    const int ch = t & 7;           // 16B chunk within 64-elem row
    const int chs = ch ^ (rh & 7);  // pre-swizzled source chunk (gload path)
    const int rowBase = by * 128;
    const int colBase = bx * 128;

    const int wv = t >> 6, wm = wv >> 1, wn = wv & 1;
    const int l = t & 63, lr = l & 15, lk = l >> 4;
    const int xr = lr & 7;          // read-side XOR key

    f32x4 acc[4][4] = {};
    float areg[4][8];               // A_F32 in-flight regs (static indexing only)

    auto loadA = [&](int k0) {
        const int kbase = kStart + k0 + ch * 8;
        #pragma unroll
        for (int it = 0; it < 4; ++it) {
            const float* src = Af + aOff + (size_t)(rowBase + rh + 32 * it) * lda + kbase;
            if (kbase + 7 < kValid) {
                float2 p0 = *(const float2*)&src[0];
                float2 p1 = *(const float2*)&src[2];
                float2 p2 = *(const float2*)&src[4];
                float2 p3 = *(const float2*)&src[6];
                areg[it][0] = p0.x; areg[it][1] = p0.y;
                areg[it][2] = p1.x; areg[it][3] = p1.y;
                areg[it][4] = p2.x; areg[it][5] = p2.y;
                areg[it][6] = p3.x; areg[it][7] = p3.y;
            } else {
                #pragma unroll
                for (int j = 0; j < 8; ++j)
                    areg[it][j] = (kbase + j < kValid) ? src[j] : 0.f;
            }
        }
    };

    // cvt_pk split: hi = RNE bf16 (bit-identical to f2bf); lo = RNE(v - hi)
    // (v - hi exact by Sterbenz). 6 VALU per 2 elems.
    auto writeA = [&]() {
        #pragma unroll
        for (int it = 0; it < 4; ++it) {
            int row = rh + 32 * it;
            unsigned hp[4], lp[4];
            #pragma unroll
            for (int p = 0; p < 4; ++p) {
                float v0 = areg[it][2 * p], v1 = areg[it][2 * p + 1];
                unsigned h = cvtpk(v0, v1);
                float h0 = ubits(h << 16);
                float h1 = ubits(h & 0xffff0000u);
                lp[p] = cvtpk(v0 - h0, v1 - h1);
                hp[p] = h;
            }
            int woff = row * 64 + (ch ^ (row & 7)) * 8;
            *(uint4*)&AsH[woff] = make_uint4(hp[0], hp[1], hp[2], hp[3]);
            *(uint4*)&AsL[woff] = make_uint4(lp[0], lp[1], lp[2], lp[3]);
        }
    };

    auto stageA_lds = [&](int k0) {
        const size_t kk = (size_t)(kStart + k0 + chs * 8);
        #pragma unroll
        for (int it = 0; it < 4; ++it) {
            size_t ao = aOff + (size_t)(rowBase + rh + 32 * it) * lda + kk;
            int dst = (rh + 32 * it) * 64 + ch * 8;
            gload16(Ahi + ao, &AsH[dst]);
            gload16(Alo + ao, &AsL[dst]);
        }
    };

    auto stageB = [&](int k0) {
        const size_t kk = (size_t)(kStart + k0 + chs * 8);
        #pragma unroll
        for (int it = 0; it < 4; ++it) {
            int bn = colBase + rh + 32 * it; bn = bn < N ? bn : N - 1;
            size_t bo = bOff + (size_t)bn * ldb + kk;
            int dst = (rh + 32 * it) * 64 + ch * 8;
            gload16(Bhi + bo, &BsH[dst]);
            gload16(Blo + bo, &BsL[dst]);
        }
    };

    if (A_F32) { loadA(0); writeA(); stageB(0); }

    for (int k0 = 0; k0 < kLen; k0 += 64) {
        if (!A_F32) { stageA_lds(k0); stageB(k0); }
        __syncthreads();                       // barrier1: tile ready
        if (A_F32 && k0 + 64 < kLen) loadA(k0 + 64);   // in flight during MFMA
        #pragma unroll
        for (int s = 0; s < 2; ++s) {
            const int c = s * 4 + lk;
            const int co = (c ^ xr) * 8;
            short8 aH[4], aL[4], bH[4], bL[4];
            #pragma unroll
            for (int i = 0; i < 4; ++i) {
                int off = (wm * 64 + i * 16 + lr) * 64 + co;
                aH[i] = *(const short8*)&AsH[off];
                aL[i] = *(const short8*)&AsL[off];
            }
            #pragma unroll
            for (int j = 0; j < 4; ++j) {
                int off = (wn * 64 + j * 16 + lr) * 64 + co;
                bH[j] = *(const short8*)&BsH[off];
                bL[j] = *(const short8*)&BsL[off];
            }
            #pragma unroll
            for (int i = 0; i < 4; ++i)
                #pragma unroll
                for (int j = 0; j < 4; ++j) {
                    acc[i][j] = __builtin_amdgcn_mfma_f32_16x16x32_bf16(aH[i], bH[j], acc[i][j], 0, 0, 0);
                    acc[i][j] = __builtin_amdgcn_mfma_f32_16x16x32_bf16(aH[i], bL[j], acc[i][j], 0, 0, 0);
                    acc[i][j] = __builtin_amdgcn_mfma_f32_16x16x32_bf16(aL[i], bH[j], acc[i][j], 0, 0, 0);
                }
        }
        __syncthreads();                       // barrier2: reads done (drains loadA)
        if (A_F32 && k0 + 64 < kLen) { writeA(); stageB(k0 + 64); }
    }

    #pragma unroll
    for (int i = 0; i < 4; ++i)
        #pragma unroll
        for (int j = 0; j < 4; ++j)
            #pragma unroll
            for (int r = 0; r < 4; ++r) {
                int row = rowBase + wm * 64 + i * 16 + lk * 4 + r;
                int col = colBase + wn * 64 + j * 16 + lr;
                if (col < N) {
                    float v = acc[i][j][r];
                    if (bias) v += bias[bias0 + col];
                    if (DO_TANH) v = tanhf(v);
                    size_t off = cOff + (size_t)row * ldc + col;
                    if (OUT_SPLIT) {
                        unsigned short hh = f2bf(v);
                        Chi[off] = hh;
                        Clo[off] = f2bf(v - bf2f(hh));
                    } else {
                        Cf[off] = v;
                    }
                }
            }
}

// ---------------------------------------------------------------------------
// Pure-bf16 MFMA GEMM (decoder path): C = [tanh](A @ B^T + bias)
// Tile 128x128, BK=64, double-buffered (2x2x16KB = 64KB), prefetch overlap,
// (row&7) chunk-XOR swizzle.
// ---------------------------------------------------------------------------
template<int DO_TANH, int OUT_BF>
__global__ __launch_bounds__(256, 2) void mfma_bf(
    const unsigned short* __restrict__ A, int lda, int aGrpK,
    const unsigned short* __restrict__ Bm, int ldb, long long bGrp,
    const float* __restrict__ bias, int biasGrp,
    float* __restrict__ Cf, unsigned short* __restrict__ Cbf,
    int ldc, long long cGrp,
    int N, int kLen)
{
    __shared__ __align__(16) unsigned short As[2][128 * 64];
    __shared__ __align__(16) unsigned short Bs[2][128 * 64];

    int bx, by, z;
    xcd_remap(bx, by, z);

    const size_t aOff = (size_t)z * aGrpK;
    const size_t bOff = (size_t)z * bGrp;
    const size_t cOff = (size_t)z * cGrp;
    const int bias0 = z * biasGrp;

    const int t = threadIdx.x;
    const int rh = t >> 3;          // 0..31
    const int ch = t & 7;
    const int chs = ch ^ (rh & 7);
    const int rowBase = by * 128;
    const int colBase = bx * 128;

    const int wv = t >> 6, wm = wv >> 1, wn = wv & 1;
    const int l = t & 63, lr = l & 15, lk = l >> 4;
    const int xr = lr & 7;

    f32x4 acc[4][4] = {};
    const int nsteps = kLen >> 6;

    auto stage = [&](int buf, int kAbs) {
        const size_t kk = (size_t)(kAbs + chs * 8);
        #pragma unroll
        for (int it = 0; it < 4; ++it) {
            int ar = rowBase + rh + 32 * it;
            gload16(A + aOff + (size_t)ar * lda + kk, &As[buf][(rh + 32 * it) * 64 + ch * 8]);
            int bn = colBase + rh + 32 * it; bn = bn < N ? bn : N - 1;
            gload16(Bm + bOff + (size_t)bn * ldb + kk, &Bs[buf][(rh + 32 * it) * 64 + ch * 8]);
        }
    };

    stage(0, 0);

    for (int s = 0; s < nsteps; ++s) {
        const int cur = s & 1;
        __syncthreads();
        if (s + 1 < nsteps) stage(cur ^ 1, (s + 1) * 64);
        #pragma unroll
        for (int hh = 0; hh < 2; ++hh) {
            const int co = ((hh * 4 + lk) ^ xr) * 8;
            short8 af[4], bf[4];
            #pragma unroll
            for (int i = 0; i < 4; ++i)
                af[i] = *(const short8*)&As[cur][(wm * 64 + i * 16 + lr) * 64 + co];
            #pragma unroll
            for (int j = 0; j < 4; ++j)
                bf[j] = *(const short8*)&Bs[cur][(wn * 64 + j * 16 + lr) * 64 + co];
            #pragma unroll
            for (int i = 0; i < 4; ++i)
                #pragma unroll
                for (int j = 0; j < 4; ++j)
                    acc[i][j] = __builtin_amdgcn_mfma_f32_16x16x32_bf16(af[i], bf[j], acc[i][j], 0, 0, 0);
        }
    }

    #pragma unroll
    for (int i = 0; i < 4; ++i)
        #pragma unroll
        for (int j = 0; j < 4; ++j)
            #pragma unroll
            for (int r = 0; r < 4; ++r) {
                int row = rowBase + wm * 64 + i * 16 + lk * 4 + r;
                int col = colBase + wn * 64 + j * 16 + lr;
                if (col < N) {
                    float v = acc[i][j][r];
                    if (bias) v += bias[bias0 + col];
                    if (DO_TANH) v = tanhf(v);
                    size_t off = cOff + (size_t)row * ldc + col;
                    if (OUT_BF) Cbf[off] = f2bf(v);
                    else        Cf[off] = v;
                }
            }
}

// ---------------------------------------------------------------------------
// weight transpose + split (+K pad): src fp32 [g][Ksrc][N] -> bf16 [g][N][Kdst]
// lo == nullptr -> hi-only (plain bf16).
// ---------------------------------------------------------------------------
__global__ void transpose_split(const float* __restrict__ src, long long sGrp,
                                unsigned short* __restrict__ hi, unsigned short* __restrict__ lo,
                                long long dGrp, int Ksrc, int Kdst, int N)
{
    __shared__ float tile[32][33];
    int g = blockIdx.z;
    int k0 = blockIdx.y * 32, n0 = blockIdx.x * 32;
    int tx = threadIdx.x & 31, ty = threadIdx.x >> 5;
    #pragma unroll
    for (int i = 0; i < 4; ++i) {
        int k = k0 + ty + 8 * i, n = n0 + tx;
        float v = 0.f;
        if (k < Ksrc && n < N) v = src[(size_t)g * sGrp + (size_t)k * N + n];
        tile[ty + 8 * i][tx] = v;
    }
    __syncthreads();
    #pragma unroll
    for (int i = 0; i < 4; ++i) {
        int n = n0 + ty + 8 * i, k = k0 + tx;
        if (n < N && k < Kdst) {
            float v = tile[tx][ty + 8 * i];
            unsigned short h = f2bf(v);
            size_t off = (size_t)g * dGrp + (size_t)n * Kdst + k;
            hi[off] = h;
            if (lo) lo[off] = f2bf(v - bf2f(h));
        }
    }
}

// combine split-K partials of K2 (8 slices): z1 = tanh(sum P[z] + b1)
__global__ void combine8_tanh(const float* __restrict__ P, const float* __restrict__ b1,
                              float* __restrict__ z1)
{
    const int MN = B_ * D1_;
    int i = (blockIdx.x * 256 + threadIdx.x) * 4;
    float4 s = *(const float4*)&P[i];
    #pragma unroll
    for (int j = 1; j < 8; ++j) {
        float4 p = *(const float4*)&P[i + j * MN];
        s.x += p.x; s.y += p.y; s.z += p.z; s.w += p.w;
    }
    float4 bb = *(const float4*)&b1[i & (D1_ - 1)];
    float4 o;
    o.x = tanhf(s.x + bb.x);
    o.y = tanhf(s.y + bb.y);
    o.z = tanhf(s.z + bb.z);
    o.w = tanhf(s.w + bb.w);
    *(float4*)&z1[i] = o;
}

// ---------------------------------------------------------------------------
// fp32 vector GEMM for the tiny GEMMs K3/K5; optional bf16 out (Shi).
// ---------------------------------------------------------------------------
__global__ __launch_bounds__(256) void gemm_bt(
    const float* __restrict__ A, int aRow, int aGrp,
    const float* __restrict__ Bm, int bGrp,
    const float* __restrict__ bias, int biasGrp,
    float* __restrict__ C, int cRow, int cGrp,
    int M, int N, int K, int doTanh,
    unsigned short* __restrict__ Shi)
{
    __shared__ float As[16][68];
    __shared__ float Bs[16][64];

    const int g = blockIdx.z;
    const float* Ag = A  + (size_t)g * aGrp;
    const float* Bg = Bm + (size_t)g * bGrp;
    const float* bg = bias + (size_t)g * biasGrp;

    const int tid = threadIdx.x;
    const int tx = tid & 15, ty = tid >> 4;
    const int rowBase = blockIdx.y * 64;
    const int colBase = blockIdx.x * 64;

    float acc[4][4] = {};

    for (int k0 = 0; k0 < K; k0 += 16) {
        #pragma unroll
        for (int i = 0; i < 4; ++i) {
            int e = tid + 256 * i;
            int r = e >> 4, kk = e & 15;
            int kg = k0 + kk;
            float v = 0.f;
            if (kg < K) v = Ag[(size_t)(rowBase + r) * aRow + kg];
            As[kk][r] = v;
        }
        #pragma unroll
        for (int i = 0; i < 4; ++i) {
            int e = tid + 256 * i;
            int kk = e >> 6, c = e & 63;
            int kg = k0 + kk, cg = colBase + c;
            float v = 0.f;
            if (kg < K && cg < N) v = Bg[(size_t)kg * N + cg];
            Bs[kk][c] = v;
        }
        __syncthreads();
        #pragma unroll
        for (int kk = 0; kk < 16; ++kk) {
            float4 a4 = *(const float4*)&As[kk][ty * 4];
            float4 b4 = *(const float4*)&Bs[kk][tx * 4];
            float av[4] = {a4.x, a4.y, a4.z, a4.w};
            float bv[4] = {b4.x, b4.y, b4.z, b4.w};
            #pragma unroll
            for (int i = 0; i < 4; ++i)
                #pragma unroll
                for (int j = 0; j < 4; ++j)
                    acc[i][j] = fmaf(av[i], bv[j], acc[i][j]);
        }
        __syncthreads();
    }

    #pragma unroll
    for (int i = 0; i < 4; ++i) {
        int row = rowBase + ty * 4 + i;
        #pragma unroll
        for (int j = 0; j < 4; ++j) {
            int col = colBase + tx * 4 + j;
            if (col < N) {
                float v = acc[i][j] + bg[col];
                if (doTanh) v = tanhf(v);
                size_t off = (size_t)g * cGrp + (size_t)row * cRow + col;
                if (Shi) Shi[off] = f2bf(v);
                else     C[off] = v;
            }
        }
    }
}

// ---------------- VQ ----------------
__global__ void vq_prep(const float* __restrict__ cb, double* __restrict__ csq,
                        float* __restrict__ csqf, double* __restrict__ acc)
{
    int i = threadIdx.x;
    double s = 0.0;
    for (int d = 0; d < D2_; ++d) {
        double v = (double)cb[i * D2_ + d];
        s = fma(v, v, s);
    }
    csq[i] = s;
    csqf[i] = (float)s;
    if (i == 0) *acc = 0.0;
}

// f32 prescore (4 rows/block) + f64 re-score of margin candidates; semantics
// identical to all-f64 argmin with first-index tie-break.
__global__ __launch_bounds__(256) void vq_kernel(
    const float* __restrict__ z, const float* __restrict__ cb,
    const double* __restrict__ csq, const float* __restrict__ csqf,
    float* __restrict__ qst_out, float* __restrict__ q_ws,
    double* __restrict__ acc)
{
    __shared__ float  zsh[4][D2_];
    __shared__ float  rmin[256];
    __shared__ int    cand[64];
    __shared__ double dval[64];
    __shared__ int    ncand;
    __shared__ int    bestidx;
    __shared__ float  lsum[256];

    const int b0 = blockIdx.x * 4;
    const int t = threadIdx.x;

    ((float*)zsh)[t]       = z[(size_t)b0 * D2_ + t];
    ((float*)zsh)[t + 256] = z[(size_t)b0 * D2_ + t + 256];
    __syncthreads();

    float sc[2][4];
    #pragma unroll
    for (int ii = 0; ii < 2; ++ii) {
        int i = t + (ii << 8);
        const float4* cr = (const float4*)(cb + (size_t)i * D2_);
        float d0 = 0.f, d1 = 0.f, d2 = 0.f, d3 = 0.f;
        #pragma unroll 4
        for (int d4 = 0; d4 < 32; ++d4) {
            float4 c4 = cr[d4];
            float4 z0 = ((const float4*)zsh[0])[d4];
            float4 z1 = ((const float4*)zsh[1])[d4];
            float4 z2 = ((const float4*)zsh[2])[d4];
            float4 z3 = ((const float4*)zsh[3])[d4];
            d0 = fmaf(c4.x, z0.x, fmaf(c4.y, z0.y, fmaf(c4.z, z0.z, fmaf(c4.w, z0.w, d0))));
            d1 = fmaf(c4.x, z1.x, fmaf(c4.y, z1.y, fmaf(c4.z, z1.z, fmaf(c4.w, z1.w, d1))));
            d2 = fmaf(c4.x, z2.x, fmaf(c4.y, z2.y, fmaf(c4.z, z2.z, fmaf(c4.w, z2.w, d2))));
            d3 = fmaf(c4.x, z3.x, fmaf(c4.y, z3.y, fmaf(c4.z, z3.z, fmaf(c4.w, z3.w, d3))));
        }
        float cs = csqf[i];
        sc[ii][0] = cs - 2.f * d0;
        sc[ii][1] = cs - 2.f * d1;
        sc[ii][2] = cs - 2.f * d2;
        sc[ii][3] = cs - 2.f * d3;
    }

    float lossAcc = 0.f;
    for (int r = 0; r < 4; ++r) {
        rmin[t] = fminf(sc[0][r], sc[1][r]);
        __syncthreads();
        for (int off = 128; off > 0; off >>= 1) {
            if (t < off) rmin[t] = fminf(rmin[t], rmin[t + off]);
            __syncthreads();
        }
        float bestv = rmin[0];
        if (t == 0) ncand = 0;
        __syncthreads();
        #pragma unroll
        for (int ii = 0; ii < 2; ++ii)
            if (sc[ii][r] <= bestv + 1e-5f) {
                int p = atomicAdd(&ncand, 1);
                if (p < 64) cand[p] = t + (ii << 8);
            }
        __syncthreads();
        int nc = ncand < 64 ? ncand : 64;
        if (t < nc) {
            int i = cand[t];
            const float* cr = cb + (size_t)i * D2_;
            double dot = 0.0;
            for (int d = 0; d < D2_; ++d)
                dot = fma((double)cr[d], (double)zsh[r][d], dot);
            dval[t] = csq[i] - 2.0 * dot;
        }
        __syncthreads();
        if (t == 0) {
            double bv = 1e300; int bi = 0x7fffffff;
            for (int j2 = 0; j2 < nc; ++j2) {
                double v = dval[j2]; int i2 = cand[j2];
                if (v < bv || (v == bv && i2 < bi)) { bv = v; bi = i2; }
            }
            bestidx = bi;
        }
        __syncthreads();
        int idx = bestidx;
        if (t < D2_) {
            float qv = cb[(size_t)idx * D2_ + t];
            size_t o = (size_t)(b0 + r) * D2_ + t;
            qst_out[o] = qv;
            q_ws[o] = qv;
            float d = qv - zsh[r][t];
            lossAcc += d * d;
        }
        __syncthreads();
    }
    lsum[t] = lossAcc;
    __syncthreads();
    for (int off = 128; off > 0; off >>= 1) {
        if (t < off) lsum[t] += lsum[t + off];
        __syncthreads();
    }
    if (t == 0) atomicAdd(acc, (double)lsum[0]);
}

__global__ void finalize_loss(const double* __restrict__ acc, float* __restrict__ out0)
{
    out0[0] = (float)(1.25 * (*acc) / (double)((size_t)B_ * D2_));
}

// ---------------------------------------------------------------------------
extern "C" void kernel_launch(void* const* d_in, const int* in_sizes, int n_in,
                              void* d_out, int out_size, void* d_ws, size_t ws_size,
                              hipStream_t stream)
{
    const float* inputs = (const float*)d_in[0];
    const float* enc_w  = (const float*)d_in[1];
    const float* enc_b  = (const float*)d_in[2];
    const float* w1     = (const float*)d_in[3];
    const float* b1     = (const float*)d_in[4];
    const float* w2     = (const float*)d_in[5];
    const float* b2     = (const float*)d_in[6];
    const float* cb     = (const float*)d_in[7];
    const float* dw1    = (const float*)d_in[8];
    const float* db1    = (const float*)d_in[9];
    const float* dw2    = (const float*)d_in[10];
    const float* db2    = (const float*)d_in[11];
    const float* dec_w  = (const float*)d_in[12];
    const float* dec_b  = (const float*)d_in[13];

    float* out = (float*)d_out;
    float* x_recon = out + 1;
    float* qst     = out + 1 + (size_t)B_ * C_ * G_;

    const size_t MB = 1u << 20;
    const size_t NEED = 172 * MB;
    dim3 blk(256);

    if (ws_size >= NEED) {
        char* W = (char*)d_ws;
        unsigned short* ewt_hi = (unsigned short*)(W + 0);         // 8MB
        unsigned short* ewt_lo = (unsigned short*)(W + 8 * MB);    // 8MB
        unsigned short* h_hi   = (unsigned short*)(W + 16 * MB);   // 32MB
        unsigned short* h_lo   = (unsigned short*)(W + 48 * MB);   // 32MB
        unsigned short* w1t_hi = (unsigned short*)(W + 80 * MB);   // 2MB
        unsigned short* w1t_lo = (unsigned short*)(W + 82 * MB);   // 2MB
        unsigned short* dw2t   = (unsigned short*)(W + 84 * MB);   // 2MB (bf16 only)
        unsigned short* dwt    = (unsigned short*)(W + 86 * MB);   // 7.65MB (bf16 only)
        float* partials = (float*)(W + 94 * MB);                   // 32MB (8 slices)
        float* z1 = (float*)(W + 126 * MB);                        // 4MB
        float* z  = (float*)(W + 130 * MB);                        // 2MB
        float* q  = (float*)(W + 132 * MB);                        // 2MB
        unsigned short* r1_bf = (unsigned short*)(W + 134 * MB);   // 2MB
        unsigned short* r_bf  = (unsigned short*)(W + 136 * MB);   // 32MB -> ends 168MB
        double* csq  = (double*)(W + 168 * MB);                    // 4KB
        double* acc  = (double*)(W + 168 * MB + 4096);
        float*  csqf = (float*)(W + 168 * MB + 4096 + 64);

        // weight prep (inputs are split on the fly in K1)
        transpose_split<<<dim3(16, 32, 8), blk, 0, stream>>>(
            enc_w, (long long)G_ * D0_, ewt_hi, ewt_lo, (long long)D0_ * KP_, G_, KP_, D0_);
        transpose_split<<<dim3(8, 128, 1), blk, 0, stream>>>(
            w1, 0, w1t_hi, w1t_lo, 0, CD_, CD_, D1_);
        transpose_split<<<dim3(128, 8, 1), blk, 0, stream>>>(
            dw2, 0, dw2t, nullptr, 0, D1_, D1_, CD_);
        transpose_split<<<dim3(31, 16, 8), blk, 0, stream>>>(
            dec_w, (long long)D0_ * G_, dwt, nullptr, (long long)G_ * D0_, D0_, D0_, G_);

        // K1: h = tanh(inputs @ enc_w + enc_b); A = raw fp32, split on the fly
        mfma_split<1, 1, 1><<<dim3(4, 32, 8), blk, 0, stream>>>(
            nullptr, nullptr, inputs, C_ * G_, G_,
            ewt_hi, ewt_lo, KP_, D0_ * KP_,
            enc_b, D0_,
            nullptr, h_hi, h_lo, CD_, 512LL,
            D0_, KP_, G_, 0);

        // K2: partials[z] = h @ w1 (split-K = 8)
        mfma_split<0, 0, 0><<<dim3(2, 32, 8), blk, 0, stream>>>(
            h_hi, h_lo, nullptr, CD_, 0,
            w1t_hi, w1t_lo, CD_, 0,
            nullptr, 0,
            partials, nullptr, nullptr, D1_, (long long)B_ * D1_,
            D1_, CD_ / 8, CD_ / 8, 1);
        combine8_tanh<<<dim3(B_ * D1_ / 1024), blk, 0, stream>>>(partials, b1, z1);

        // K3: z = tanh(z1 @ w2 + b2)  (fp32)
        gemm_bt<<<dim3(2, 64, 1), blk, 0, stream>>>(
            z1, D1_, 0, w2, 0, b2, 0, z, D2_, 0, B_, D2_, D1_, 1, nullptr);

        // VQ
        vq_prep<<<dim3(1), dim3(K_), 0, stream>>>(cb, csq, csqf, acc);
        vq_kernel<<<dim3(B_ / 4), blk, 0, stream>>>(z, cb, csq, csqf, qst, q, acc);

        // K5: r1 = tanh(q @ dw1 + db1)  (fp32 compute, bf16 out)
        gemm_bt<<<dim3(4, 64, 1), blk, 0, stream>>>(
            q, D2_, 0, dw1, 0, db1, 0, nullptr, D1_, 0, B_, D1_, D2_, 1, r1_bf);

        // K6: r = tanh(r1 @ dw2 + db2), pure bf16
        mfma_bf<1, 1><<<dim3(32, 32, 1), blk, 0, stream>>>(
            r1_bf, D1_, 0,
            dw2t, D1_, 0,
            db2, 0,
            nullptr, r_bf, CD_, 0LL,
            CD_, D1_);

        // K7: x_recon = r @ dec_w + dec_b (grouped, pure bf16, fp32 out)
        mfma_bf<0, 0><<<dim3(8, 32, 8), blk, 0, stream>>>(
            r_bf, CD_, 512,
            dwt, D0_, (long long)G_ * D0_,
            dec_b, G_,
            x_recon, nullptr, C_ * G_, (long long)G_,
            G_, D0_);

        finalize_loss<<<dim3(1), dim3(1), 0, stream>>>(acc, out);
    } else {
        // -------- fallback: fp32 path --------
        float*  h   = (float*)d_ws;
        float*  z1  = h  + (size_t)B_ * CD_;
        float*  z   = z1 + (size_t)B_ * D1_;
        float*  q   = z  + (size_t)B_ * D2_;
        double* csq = (double*)(q + (size_t)B_ * D2_);
        double* acc = csq + K_;
        float*  csqf = (float*)(acc + 8);

        gemm_bt<<<dim3(D0_ / 64, B_ / 64, C_), blk, 0, stream>>>(
            inputs, C_ * G_, G_, enc_w, G_ * D0_, enc_b, D0_,
            h, CD_, D0_, B_, D0_, G_, 1, nullptr);
        gemm_bt<<<dim3(D1_ / 64, B_ / 64, 1), blk, 0, stream>>>(
            h, CD_, 0, w1, 0, b1, 0, z1, D1_, 0, B_, D1_, CD_, 1, nullptr);
        gemm_bt<<<dim3(D2_ / 64, B_ / 64, 1), blk, 0, stream>>>(
            z1, D1_, 0, w2, 0, b2, 0, z, D2_, 0, B_, D2_, D1_, 1, nullptr);
        vq_prep<<<dim3(1), dim3(K_), 0, stream>>>(cb, csq, csqf, acc);
        vq_kernel<<<dim3(B_ / 4), blk, 0, stream>>>(z, cb, csq, csqf, qst, q, acc);
        gemm_bt<<<dim3(D1_ / 64, B_ / 64, 1), blk, 0, stream>>>(
            q, D2_, 0, dw1, 0, db1, 0, z1, D1_, 0, B_, D1_, D2_, 1, nullptr);
        gemm_bt<<<dim3(CD_ / 64, B_ / 64, 1), blk, 0, stream>>>(
            z1, D1_, 0, dw2, 0, db2, 0, h, CD_, 0, B_, CD_, D1_, 1, nullptr);
        gemm_bt<<<dim3((G_ + 63) / 64, B_ / 64, C_), blk, 0, stream>>>(
            h, CD_, D0_, dec_w, D0_ * G_, dec_b, G_,
            x_recon, C_ * G_, G_, B_, G_, D0_, 0, nullptr);
        finalize_loss<<<dim3(1), dim3(1), 0, stream>>>(acc, out);
    }
}